// Round 1
// baseline (2892.382 us; speedup 1.0000x reference)
//
#include <hip/hip_runtime.h>

// Problem constants (from reference): N=50000, D=128 (both layers), K=256.
#define D_FEAT 128
#define K_DIM  256

__device__ __forceinline__ float atomAddF(float* p, float v) {
    // Agent-scope relaxed fadd -> global_atomic_add_f32 on gfx950 (avoid CAS loop)
    return __hip_atomic_fetch_add(p, v, __ATOMIC_RELAXED, __HIP_MEMORY_SCOPE_AGENT);
}

// One edge handled by 32 lanes; each lane moves one float4 (128 floats/row).
// DELTA=false: msg = feat[src]        (history etype, feat = HBar)
// DELTA=true : msg = feat[src]-featBar[src]  (sampled etype, feat = H)
template<bool DELTA>
__global__ __launch_bounds__(256)
void scatter_kernel(const float4* __restrict__ feat,
                    const float4* __restrict__ featBar,
                    const int* __restrict__ src, const int* __restrict__ dst,
                    int E, float* __restrict__ acc, float* __restrict__ cnt) {
    int gid  = blockIdx.x * blockDim.x + threadIdx.x;
    int e    = gid >> 5;
    int lane = gid & 31;
    if (e >= E) return;
    int s = src[e];
    int d = dst[e];
    float4 v = feat[(size_t)s * 32 + lane];
    if (DELTA) {
        float4 w = featBar[(size_t)s * 32 + lane];
        v.x -= w.x; v.y -= w.y; v.z -= w.z; v.w -= w.w;
    }
    float* a = acc + (size_t)d * D_FEAT + lane * 4;
    atomAddF(a + 0, v.x);
    atomAddF(a + 1, v.y);
    atomAddF(a + 2, v.z);
    atomAddF(a + 3, v.w);
    if (lane == 0) atomAddF(cnt + d, 1.0f);
}

// z[i] = [ H[i] (128) | accH[i]/max(cntH,1) + accS[i]/max(cntS,1) (128) ]
__global__ __launch_bounds__(256)
void build_z(const float* __restrict__ H,
             const float* __restrict__ accH, const float* __restrict__ accS,
             const float* __restrict__ cntH, const float* __restrict__ cntS,
             float* __restrict__ z) {
    int i = blockIdx.x;
    int t = threadIdx.x;
    if (t < D_FEAT) {
        z[(size_t)i * K_DIM + t] = H[(size_t)i * D_FEAT + t];
    } else {
        int j = t - D_FEAT;
        float rH = 1.0f / fmaxf(cntH[i], 1.0f);
        float rS = 1.0f / fmaxf(cntS[i], 1.0f);
        z[(size_t)i * K_DIM + t] =
            accH[(size_t)i * D_FEAT + j] * rH + accS[(size_t)i * D_FEAT + j] * rS;
    }
}

// out[m, c] = relu( sum_k z[m,k] * W[c,k] + bias[c] ),  K = 256 fixed.
// BM=BN=64, BK=64 tiles; 256 threads; each thread computes a 4x4 micro-tile.
template<int COLS>
__global__ __launch_bounds__(256)
void gemm_relu(const float* __restrict__ Z, const float* __restrict__ W,
               const float* __restrict__ bias, float* __restrict__ out, int n) {
    __shared__ float As[64][68];  // As[k][m] (transposed for vector micro reads)
    __shared__ float Bs[64][68];  // Bs[k][c]
    int t  = threadIdx.x;
    int ty = t >> 4;        // 0..15 -> row group
    int tx = t & 15;        // 0..15 -> col group
    int m0 = blockIdx.x * 64;
    int n0 = blockIdx.y * 64;

    float acc[4][4] = {};

    int lr = t >> 4;         // 0..15 loader row
    int lc = (t & 15) * 4;   // 0..60 loader col (float4)

    for (int k0 = 0; k0 < K_DIM; k0 += 64) {
        #pragma unroll
        for (int it = 0; it < 4; ++it) {
            int row = lr + it * 16;
            int gm  = m0 + row;
            float4 v = (gm < n) ? *(const float4*)&Z[(size_t)gm * K_DIM + k0 + lc]
                                : make_float4(0.f, 0.f, 0.f, 0.f);
            As[lc + 0][row] = v.x; As[lc + 1][row] = v.y;
            As[lc + 2][row] = v.z; As[lc + 3][row] = v.w;
        }
        #pragma unroll
        for (int it = 0; it < 4; ++it) {
            int row = lr + it * 16;
            int gc  = n0 + row;
            float4 v = (gc < COLS) ? *(const float4*)&W[(size_t)gc * K_DIM + k0 + lc]
                                   : make_float4(0.f, 0.f, 0.f, 0.f);
            Bs[lc + 0][row] = v.x; Bs[lc + 1][row] = v.y;
            Bs[lc + 2][row] = v.z; Bs[lc + 3][row] = v.w;
        }
        __syncthreads();
        #pragma unroll
        for (int k = 0; k < 64; ++k) {
            float4 a  = *(const float4*)&As[k][ty * 4];
            float4 bv = *(const float4*)&Bs[k][tx * 4];
            float av[4] = {a.x, a.y, a.z, a.w};
            float bw[4] = {bv.x, bv.y, bv.z, bv.w};
            #pragma unroll
            for (int i = 0; i < 4; ++i)
                #pragma unroll
                for (int j = 0; j < 4; ++j)
                    acc[i][j] += av[i] * bw[j];
        }
        __syncthreads();
    }

    #pragma unroll
    for (int i = 0; i < 4; ++i) {
        int gm = m0 + ty * 4 + i;
        if (gm >= n) continue;
        #pragma unroll
        for (int j = 0; j < 4; ++j) {
            int gc = n0 + tx * 4 + j;
            if (gc >= COLS) continue;
            float v = acc[i][j] + bias[gc];
            out[(size_t)gm * COLS + gc] = fmaxf(v, 0.0f);
        }
    }
}

extern "C" void kernel_launch(void* const* d_in, const int* in_sizes, int n_in,
                              void* d_out, int out_size, void* d_ws, size_t ws_size,
                              hipStream_t stream) {
    const float* x     = (const float*)d_in[0];
    const float* hbar0 = (const float*)d_in[1];
    const float* hbar1 = (const float*)d_in[2];
    const float* W0    = (const float*)d_in[3];
    const float* b0    = (const float*)d_in[4];
    const float* W1    = (const float*)d_in[5];
    const float* b1    = (const float*)d_in[6];
    const int* hs0 = (const int*)d_in[7];
    const int* hd0 = (const int*)d_in[8];
    const int* ss0 = (const int*)d_in[9];
    const int* sd0 = (const int*)d_in[10];
    const int* hs1 = (const int*)d_in[11];
    const int* hd1 = (const int*)d_in[12];
    const int* ss1 = (const int*)d_in[13];
    const int* sd1 = (const int*)d_in[14];

    const int n  = in_sizes[0] / D_FEAT;   // 50000
    const int EH = in_sizes[7];            // 500000
    const int ES = in_sizes[9];            // 250000

    float* ws   = (float*)d_ws;
    float* accH = ws;                                  // n*128
    float* accS = accH + (size_t)n * D_FEAT;           // n*128
    float* cntH = accS + (size_t)n * D_FEAT;           // n
    float* cntS = cntH + n;                            // n
    float* h1   = cntS + n;                            // n*128
    float* z    = h1 + (size_t)n * D_FEAT;             // n*256
    const size_t zero_bytes = ((size_t)n * 2 * D_FEAT + 2 * (size_t)n) * sizeof(float);

    dim3 blk(256);
    int scatterH_blocks = (EH * 32 + 255) / 256;
    int scatterS_blocks = (ES * 32 + 255) / 256;
    int gemm_m_blocks   = (n + 63) / 64;

    // ---------------- Layer 0 ----------------
    hipMemsetAsync(accH, 0, zero_bytes, stream);
    scatter_kernel<false><<<scatterH_blocks, blk, 0, stream>>>(
        (const float4*)hbar0, nullptr, hs0, hd0, EH, accH, cntH);
    scatter_kernel<true><<<scatterS_blocks, blk, 0, stream>>>(
        (const float4*)x, (const float4*)hbar0, ss0, sd0, ES, accS, cntS);
    build_z<<<n, blk, 0, stream>>>(x, accH, accS, cntH, cntS, z);
    gemm_relu<128><<<dim3(gemm_m_blocks, 2), blk, 0, stream>>>(z, W0, b0, h1, n);

    // ---------------- Layer 1 ----------------
    hipMemsetAsync(accH, 0, zero_bytes, stream);
    scatter_kernel<false><<<scatterH_blocks, blk, 0, stream>>>(
        (const float4*)hbar1, nullptr, hs1, hd1, EH, accH, cntH);
    scatter_kernel<true><<<scatterS_blocks, blk, 0, stream>>>(
        (const float4*)h1, (const float4*)hbar1, ss1, sd1, ES, accS, cntS);
    build_z<<<n, blk, 0, stream>>>(h1, accH, accS, cntH, cntS, z);
    gemm_relu<47><<<dim3(gemm_m_blocks, 1), blk, 0, stream>>>(z, W1, b1, (float*)d_out, n);
}

// Round 2
// 774.058 us; speedup vs baseline: 3.7366x; 3.7366x over previous
//
#include <hip/hip_runtime.h>

// N=50000, D=128 (both layers), K=256, EH=500000, ES=250000.
#define D_FEAT 128
#define K_DIM  256

// ---------------- CSR build ----------------

__global__ __launch_bounds__(256)
void hist_kernel(const int* __restrict__ dst, int E, int* __restrict__ cnt) {
    int i = blockIdx.x * blockDim.x + threadIdx.x;
    if (i < E) atomicAdd(&cnt[dst[i]], 1);
}

// gridDim.x == 2: block 0 scans hist counts, block 1 scans samp counts.
__global__ __launch_bounds__(1024)
void scan_kernel(const int* __restrict__ cntH, int* __restrict__ rpH, int* __restrict__ curH,
                 const int* __restrict__ cntS, int* __restrict__ rpS, int* __restrict__ curS,
                 int n) {
    const int* cnt = (blockIdx.x == 0) ? cntH : cntS;
    int* rp  = (blockIdx.x == 0) ? rpH : rpS;
    int* cur = (blockIdx.x == 0) ? curH : curS;

    __shared__ int part[1024];
    int t = threadIdx.x;
    int chunk = (n + 1023) >> 10;
    int lo = t * chunk;
    int hi = min(n, lo + chunk);
    int s = 0;
    for (int i = lo; i < hi; ++i) s += cnt[i];
    part[t] = s;
    __syncthreads();
    // Hillis-Steele inclusive scan over 1024 partials
    for (int off = 1; off < 1024; off <<= 1) {
        int v = (t >= off) ? part[t - off] : 0;
        __syncthreads();
        part[t] += v;
        __syncthreads();
    }
    int run = (t == 0) ? 0 : part[t - 1];
    for (int i = lo; i < hi; ++i) {
        rp[i] = run;
        cur[i] = run;
        run += cnt[i];
    }
    if (hi == n) rp[n] = run;   // all trailing threads write the same total
}

__global__ __launch_bounds__(256)
void order_kernel(const int* __restrict__ src, const int* __restrict__ dst, int E,
                  int* __restrict__ cursor, int* __restrict__ srcSorted) {
    int i = blockIdx.x * blockDim.x + threadIdx.x;
    if (i < E) {
        int p = atomicAdd(&cursor[dst[i]], 1);
        srcSorted[p] = src[i];
    }
}

// ---------------- fused aggregation + z assembly ----------------
// 32 lanes per node (each lane owns one float4 of the 128-float row);
// 256 threads/block -> 8 nodes per block.
// z[i] = [ H[i] | sum_hist HBar[s]/cH + sum_samp (H[s]-HBar[s])/cS ]
__global__ __launch_bounds__(256)
void aggregate_z(const float4* __restrict__ H, const float4* __restrict__ HBar,
                 const int* __restrict__ rpH, const int* __restrict__ srcH,
                 const int* __restrict__ rpS, const int* __restrict__ srcS,
                 float4* __restrict__ z, int n) {
    int g    = blockIdx.x * 8 + (threadIdx.x >> 5);
    int lane = threadIdx.x & 31;
    if (g >= n) return;

    int hb = rpH[g], he = rpH[g + 1];
    int sb = rpS[g], se = rpS[g + 1];

    float4 aH = make_float4(0.f, 0.f, 0.f, 0.f);
    for (int e = hb; e < he; ++e) {
        float4 v = HBar[(size_t)srcH[e] * 32 + lane];
        aH.x += v.x; aH.y += v.y; aH.z += v.z; aH.w += v.w;
    }
    float4 aD = make_float4(0.f, 0.f, 0.f, 0.f);
    for (int e = sb; e < se; ++e) {
        int s = srcS[e];
        float4 v = H[(size_t)s * 32 + lane];
        float4 w = HBar[(size_t)s * 32 + lane];
        aD.x += v.x - w.x; aD.y += v.y - w.y;
        aD.z += v.z - w.z; aD.w += v.w - w.w;
    }
    float rH = 1.0f / fmaxf((float)(he - hb), 1.0f);
    float rS = 1.0f / fmaxf((float)(se - sb), 1.0f);
    float4 hn = make_float4(aH.x * rH + aD.x * rS, aH.y * rH + aD.y * rS,
                            aH.z * rH + aD.z * rS, aH.w * rH + aD.w * rS);

    z[(size_t)g * 64 + lane]      = H[(size_t)g * 32 + lane];  // left half: H row
    z[(size_t)g * 64 + 32 + lane] = hn;                        // right half: h_neigh
}

// ---------------- GEMM + bias + relu ----------------
// out[m,c] = relu( sum_k z[m,k]*W[c,k] + bias[c] ), K=256.
template<int COLS>
__global__ __launch_bounds__(256)
void gemm_relu(const float* __restrict__ Z, const float* __restrict__ W,
               const float* __restrict__ bias, float* __restrict__ out, int n) {
    __shared__ float As[64][68];  // As[k][m]
    __shared__ float Bs[64][68];  // Bs[k][c]
    int t  = threadIdx.x;
    int ty = t >> 4;
    int tx = t & 15;
    int m0 = blockIdx.x * 64;
    int n0 = blockIdx.y * 64;

    float acc[4][4] = {};

    int lr = t >> 4;
    int lc = (t & 15) * 4;

    for (int k0 = 0; k0 < K_DIM; k0 += 64) {
        #pragma unroll
        for (int it = 0; it < 4; ++it) {
            int row = lr + it * 16;
            int gm  = m0 + row;
            float4 v = (gm < n) ? *(const float4*)&Z[(size_t)gm * K_DIM + k0 + lc]
                                : make_float4(0.f, 0.f, 0.f, 0.f);
            As[lc + 0][row] = v.x; As[lc + 1][row] = v.y;
            As[lc + 2][row] = v.z; As[lc + 3][row] = v.w;
        }
        #pragma unroll
        for (int it = 0; it < 4; ++it) {
            int row = lr + it * 16;
            int gc  = n0 + row;
            float4 v = (gc < COLS) ? *(const float4*)&W[(size_t)gc * K_DIM + k0 + lc]
                                   : make_float4(0.f, 0.f, 0.f, 0.f);
            Bs[lc + 0][row] = v.x; Bs[lc + 1][row] = v.y;
            Bs[lc + 2][row] = v.z; Bs[lc + 3][row] = v.w;
        }
        __syncthreads();
        #pragma unroll
        for (int k = 0; k < 64; ++k) {
            float4 a  = *(const float4*)&As[k][ty * 4];
            float4 bv = *(const float4*)&Bs[k][tx * 4];
            float av[4] = {a.x, a.y, a.z, a.w};
            float bw[4] = {bv.x, bv.y, bv.z, bv.w};
            #pragma unroll
            for (int i = 0; i < 4; ++i)
                #pragma unroll
                for (int j = 0; j < 4; ++j)
                    acc[i][j] += av[i] * bw[j];
        }
        __syncthreads();
    }

    #pragma unroll
    for (int i = 0; i < 4; ++i) {
        int gm = m0 + ty * 4 + i;
        if (gm >= n) continue;
        #pragma unroll
        for (int j = 0; j < 4; ++j) {
            int gc = n0 + tx * 4 + j;
            if (gc >= COLS) continue;
            float v = acc[i][j] + bias[gc];
            out[(size_t)gm * COLS + gc] = fmaxf(v, 0.0f);
        }
    }
}

extern "C" void kernel_launch(void* const* d_in, const int* in_sizes, int n_in,
                              void* d_out, int out_size, void* d_ws, size_t ws_size,
                              hipStream_t stream) {
    const float* x     = (const float*)d_in[0];
    const float* hbar0 = (const float*)d_in[1];
    const float* hbar1 = (const float*)d_in[2];
    const float* W0    = (const float*)d_in[3];
    const float* b0    = (const float*)d_in[4];
    const float* W1    = (const float*)d_in[5];
    const float* b1    = (const float*)d_in[6];
    const int* hs0 = (const int*)d_in[7];
    const int* hd0 = (const int*)d_in[8];
    const int* ss0 = (const int*)d_in[9];
    const int* sd0 = (const int*)d_in[10];
    const int* hs1 = (const int*)d_in[11];
    const int* hd1 = (const int*)d_in[12];
    const int* ss1 = (const int*)d_in[13];
    const int* sd1 = (const int*)d_in[14];

    const int n  = in_sizes[0] / D_FEAT;   // 50000
    const int EH = in_sizes[7];            // 500000
    const int ES = in_sizes[9];            // 250000

    // ---- workspace layout (ints first, then 16B-aligned floats) ----
    int* cntH = (int*)d_ws;                 // n   (cntH,cntS adjacent -> one memset)
    int* cntS = cntH + n;                   // n
    int* rpH  = cntS + n;                   // n+1
    int* rpS  = rpH + (n + 1);              // n+1
    int* curH = rpS + (n + 1);              // n
    int* curS = curH + n;                   // n
    int* srcH = curS + n;                   // EH
    int* srcS = srcH + EH;                  // ES
    size_t int_words = (size_t)(6 * n + 2) + EH + ES;
    int_words = (int_words + 3) & ~(size_t)3;          // 16 B align
    float* h1 = (float*)d_ws + int_words;              // n*128
    float* z  = h1 + (size_t)n * D_FEAT;               // n*256

    dim3 blk(256);
    int ehb = (EH + 255) / 256;
    int esb = (ES + 255) / 256;
    int agg_blocks    = (n + 7) / 8;
    int gemm_m_blocks = (n + 63) / 64;

    // ---------------- Layer 0 ----------------
    hipMemsetAsync(cntH, 0, (size_t)2 * n * sizeof(int), stream);
    hist_kernel<<<ehb, blk, 0, stream>>>(hd0, EH, cntH);
    hist_kernel<<<esb, blk, 0, stream>>>(sd0, ES, cntS);
    scan_kernel<<<2, 1024, 0, stream>>>(cntH, rpH, curH, cntS, rpS, curS, n);
    order_kernel<<<ehb, blk, 0, stream>>>(hs0, hd0, EH, curH, srcH);
    order_kernel<<<esb, blk, 0, stream>>>(ss0, sd0, ES, curS, srcS);
    aggregate_z<<<agg_blocks, blk, 0, stream>>>(
        (const float4*)x, (const float4*)hbar0, rpH, srcH, rpS, srcS, (float4*)z, n);
    gemm_relu<128><<<dim3(gemm_m_blocks, 2), blk, 0, stream>>>(z, W0, b0, h1, n);

    // ---------------- Layer 1 ----------------
    hipMemsetAsync(cntH, 0, (size_t)2 * n * sizeof(int), stream);
    hist_kernel<<<ehb, blk, 0, stream>>>(hd1, EH, cntH);
    hist_kernel<<<esb, blk, 0, stream>>>(sd1, ES, cntS);
    scan_kernel<<<2, 1024, 0, stream>>>(cntH, rpH, curH, cntS, rpS, curS, n);
    order_kernel<<<ehb, blk, 0, stream>>>(hs1, hd1, EH, curH, srcH);
    order_kernel<<<esb, blk, 0, stream>>>(ss1, sd1, ES, curS, srcS);
    aggregate_z<<<agg_blocks, blk, 0, stream>>>(
        (const float4*)h1, (const float4*)hbar1, rpH, srcH, rpS, srcS, (float4*)z, n);
    gemm_relu<47><<<dim3(gemm_m_blocks, 1), blk, 0, stream>>>(z, W1, b1, (float*)d_out, n);
}

// Round 3
// 557.121 us; speedup vs baseline: 5.1917x; 1.3894x over previous
//
#include <hip/hip_runtime.h>

// N=50000, D=128 (both layers), K=256, EH=500000, ES=250000.
#define D_FEAT 128
#define K_DIM  256

// ---------------- CSR build ----------------

// One dispatch histograms both etypes: [0,EH) -> cntH, [EH,EH+ES) -> cntS.
__global__ __launch_bounds__(256)
void hist_both(const int* __restrict__ hd, int EH, int* __restrict__ cntH,
               const int* __restrict__ sd, int ES, int* __restrict__ cntS) {
    int i = blockIdx.x * blockDim.x + threadIdx.x;
    if (i < EH) {
        atomicAdd(&cntH[hd[i]], 1);
    } else {
        int j = i - EH;
        if (j < ES) atomicAdd(&cntS[sd[j]], 1);
    }
}

// 3-phase exclusive scan over cntH and cntS (grid.y selects etype).
// 1024 elements per block -> nb = ceil(n/1024) blocks per etype.
__global__ __launch_bounds__(256)
void scan_phase1(const int* __restrict__ cntH, const int* __restrict__ cntS,
                 int* __restrict__ blockSums, int n, int nb) {
    const int* cnt = blockIdx.y ? cntS : cntH;
    int t = threadIdx.x;
    int base = blockIdx.x * 1024 + t * 4;
    int s = 0;
    #pragma unroll
    for (int i = 0; i < 4; ++i) { int g = base + i; if (g < n) s += cnt[g]; }
    __shared__ int sh[256];
    sh[t] = s;
    __syncthreads();
    for (int off = 128; off > 0; off >>= 1) {
        if (t < off) sh[t] += sh[t + off];
        __syncthreads();
    }
    if (t == 0) blockSums[blockIdx.y * nb + blockIdx.x] = sh[0];
}

// Single small block: exclusive-scan the per-block sums of both etypes.
__global__ __launch_bounds__(128)
void scan_phase2(int* __restrict__ blockSums, int nb) {
    __shared__ int sh[128];
    int t = threadIdx.x;
    if (t < 2 * nb) sh[t] = blockSums[t];
    __syncthreads();
    if (t < 2) {
        int run = 0;
        for (int i = 0; i < nb; ++i) { int v = sh[t * nb + i]; sh[t * nb + i] = run; run += v; }
    }
    __syncthreads();
    if (t < 2 * nb) blockSums[t] = sh[t];
}

__global__ __launch_bounds__(256)
void scan_phase3(const int* __restrict__ cntH, const int* __restrict__ cntS,
                 const int* __restrict__ blockSums,
                 int* __restrict__ rpH, int* __restrict__ curH,
                 int* __restrict__ rpS, int* __restrict__ curS, int n, int nb) {
    const int* cnt = blockIdx.y ? cntS : cntH;
    int* rp  = blockIdx.y ? rpS : rpH;
    int* cur = blockIdx.y ? curS : curH;
    int t = threadIdx.x;
    int base = blockIdx.x * 1024 + t * 4;
    int v[4];
    int s = 0;
    #pragma unroll
    for (int i = 0; i < 4; ++i) { int g = base + i; v[i] = (g < n) ? cnt[g] : 0; s += v[i]; }
    __shared__ int sh[256];
    sh[t] = s;
    __syncthreads();
    for (int off = 1; off < 256; off <<= 1) {
        int x = (t >= off) ? sh[t - off] : 0;
        __syncthreads();
        sh[t] += x;
        __syncthreads();
    }
    int excl = blockSums[blockIdx.y * nb + blockIdx.x] + (t ? sh[t - 1] : 0);
    #pragma unroll
    for (int i = 0; i < 4; ++i) {
        int g = base + i;
        if (g < n) {
            rp[g] = excl; cur[g] = excl;
            excl += v[i];
            if (g == n - 1) rp[n] = excl;
        }
    }
}

// One dispatch reorders both etypes.
__global__ __launch_bounds__(256)
void order_both(const int* __restrict__ hs, const int* __restrict__ hd, int EH,
                int* __restrict__ curH, int* __restrict__ srcH,
                const int* __restrict__ ss, const int* __restrict__ sd, int ES,
                int* __restrict__ curS, int* __restrict__ srcS) {
    int i = blockIdx.x * blockDim.x + threadIdx.x;
    if (i < EH) {
        int p = atomicAdd(&curH[hd[i]], 1);
        srcH[p] = hs[i];
    } else {
        int j = i - EH;
        if (j < ES) {
            int p = atomicAdd(&curS[sd[j]], 1);
            srcS[p] = ss[j];
        }
    }
}

// ---------------- fused aggregation + z assembly ----------------
// 32 lanes per node (each lane owns one float4 of the 128-float row).
__global__ __launch_bounds__(256)
void aggregate_z(const float4* __restrict__ H, const float4* __restrict__ HBar,
                 const int* __restrict__ rpH, const int* __restrict__ srcH,
                 const int* __restrict__ rpS, const int* __restrict__ srcS,
                 float4* __restrict__ z, int n) {
    int g    = blockIdx.x * 8 + (threadIdx.x >> 5);
    int lane = threadIdx.x & 31;
    if (g >= n) return;

    int hb = rpH[g], he = rpH[g + 1];
    int sb = rpS[g], se = rpS[g + 1];

    float4 aH = make_float4(0.f, 0.f, 0.f, 0.f);
    for (int e = hb; e < he; ++e) {
        float4 v = HBar[(size_t)srcH[e] * 32 + lane];
        aH.x += v.x; aH.y += v.y; aH.z += v.z; aH.w += v.w;
    }
    float4 aD = make_float4(0.f, 0.f, 0.f, 0.f);
    for (int e = sb; e < se; ++e) {
        int s = srcS[e];
        float4 v = H[(size_t)s * 32 + lane];
        float4 w = HBar[(size_t)s * 32 + lane];
        aD.x += v.x - w.x; aD.y += v.y - w.y;
        aD.z += v.z - w.z; aD.w += v.w - w.w;
    }
    float rH = 1.0f / fmaxf((float)(he - hb), 1.0f);
    float rS = 1.0f / fmaxf((float)(se - sb), 1.0f);
    float4 hn = make_float4(aH.x * rH + aD.x * rS, aH.y * rH + aD.y * rS,
                            aH.z * rH + aD.z * rS, aH.w * rH + aD.w * rS);

    z[(size_t)g * 64 + lane]      = H[(size_t)g * 32 + lane];
    z[(size_t)g * 64 + 32 + lane] = hn;
}

// ---------------- GEMM + bias + relu ----------------
template<int COLS>
__global__ __launch_bounds__(256)
void gemm_relu(const float* __restrict__ Z, const float* __restrict__ W,
               const float* __restrict__ bias, float* __restrict__ out, int n) {
    __shared__ float As[64][68];  // As[k][m]
    __shared__ float Bs[64][68];  // Bs[k][c]
    int t  = threadIdx.x;
    int ty = t >> 4;
    int tx = t & 15;
    int m0 = blockIdx.x * 64;
    int n0 = blockIdx.y * 64;

    float acc[4][4] = {};

    int lr = t >> 4;
    int lc = (t & 15) * 4;

    for (int k0 = 0; k0 < K_DIM; k0 += 64) {
        #pragma unroll
        for (int it = 0; it < 4; ++it) {
            int row = lr + it * 16;
            int gm  = m0 + row;
            float4 v = (gm < n) ? *(const float4*)&Z[(size_t)gm * K_DIM + k0 + lc]
                                : make_float4(0.f, 0.f, 0.f, 0.f);
            As[lc + 0][row] = v.x; As[lc + 1][row] = v.y;
            As[lc + 2][row] = v.z; As[lc + 3][row] = v.w;
        }
        #pragma unroll
        for (int it = 0; it < 4; ++it) {
            int row = lr + it * 16;
            int gc  = n0 + row;
            float4 v = (gc < COLS) ? *(const float4*)&W[(size_t)gc * K_DIM + k0 + lc]
                                   : make_float4(0.f, 0.f, 0.f, 0.f);
            Bs[lc + 0][row] = v.x; Bs[lc + 1][row] = v.y;
            Bs[lc + 2][row] = v.z; Bs[lc + 3][row] = v.w;
        }
        __syncthreads();
        #pragma unroll
        for (int k = 0; k < 64; ++k) {
            float4 a  = *(const float4*)&As[k][ty * 4];
            float4 bv = *(const float4*)&Bs[k][tx * 4];
            float av[4] = {a.x, a.y, a.z, a.w};
            float bw[4] = {bv.x, bv.y, bv.z, bv.w};
            #pragma unroll
            for (int i = 0; i < 4; ++i)
                #pragma unroll
                for (int j = 0; j < 4; ++j)
                    acc[i][j] += av[i] * bw[j];
        }
        __syncthreads();
    }

    #pragma unroll
    for (int i = 0; i < 4; ++i) {
        int gm = m0 + ty * 4 + i;
        if (gm >= n) continue;
        #pragma unroll
        for (int j = 0; j < 4; ++j) {
            int gc = n0 + tx * 4 + j;
            if (gc >= COLS) continue;
            float v = acc[i][j] + bias[gc];
            out[(size_t)gm * COLS + gc] = fmaxf(v, 0.0f);
        }
    }
}

extern "C" void kernel_launch(void* const* d_in, const int* in_sizes, int n_in,
                              void* d_out, int out_size, void* d_ws, size_t ws_size,
                              hipStream_t stream) {
    const float* x     = (const float*)d_in[0];
    const float* hbar0 = (const float*)d_in[1];
    const float* hbar1 = (const float*)d_in[2];
    const float* W0    = (const float*)d_in[3];
    const float* b0    = (const float*)d_in[4];
    const float* W1    = (const float*)d_in[5];
    const float* b1    = (const float*)d_in[6];
    const int* hs0 = (const int*)d_in[7];
    const int* hd0 = (const int*)d_in[8];
    const int* ss0 = (const int*)d_in[9];
    const int* sd0 = (const int*)d_in[10];
    const int* hs1 = (const int*)d_in[11];
    const int* hd1 = (const int*)d_in[12];
    const int* ss1 = (const int*)d_in[13];
    const int* sd1 = (const int*)d_in[14];

    const int n  = in_sizes[0] / D_FEAT;   // 50000
    const int EH = in_sizes[7];            // 500000
    const int ES = in_sizes[9];            // 250000
    const int nb = (n + 1023) / 1024;      // 49 blocks per etype scan

    // ---- workspace layout ----
    int* cntH = (int*)d_ws;                 // n
    int* cntS = cntH + n;                   // n
    int* rpH  = cntS + n;                   // n+1
    int* rpS  = rpH + (n + 1);              // n+1
    int* curH = rpS + (n + 1);              // n
    int* curS = curH + n;                   // n
    int* bsum = curS + n;                   // 2*nb
    int* srcH = bsum + 2 * nb;              // EH
    int* srcS = srcH + EH;                  // ES
    size_t int_words = (size_t)(6 * n + 2) + 2 * nb + EH + ES;
    int_words = (int_words + 3) & ~(size_t)3;          // 16 B align
    float* h1 = (float*)d_ws + int_words;              // n*128
    float* z  = h1 + (size_t)n * D_FEAT;               // n*256

    dim3 blk(256);
    int histb = (EH + ES + 255) / 256;
    int agg_blocks    = (n + 7) / 8;
    int gemm_m_blocks = (n + 63) / 64;

    // ---------------- Layer 0 ----------------
    hipMemsetAsync(cntH, 0, (size_t)2 * n * sizeof(int), stream);
    hist_both<<<histb, blk, 0, stream>>>(hd0, EH, cntH, sd0, ES, cntS);
    scan_phase1<<<dim3(nb, 2), blk, 0, stream>>>(cntH, cntS, bsum, n, nb);
    scan_phase2<<<1, 128, 0, stream>>>(bsum, nb);
    scan_phase3<<<dim3(nb, 2), blk, 0, stream>>>(cntH, cntS, bsum, rpH, curH, rpS, curS, n, nb);
    order_both<<<histb, blk, 0, stream>>>(hs0, hd0, EH, curH, srcH, ss0, sd0, ES, curS, srcS);
    aggregate_z<<<agg_blocks, blk, 0, stream>>>(
        (const float4*)x, (const float4*)hbar0, rpH, srcH, rpS, srcS, (float4*)z, n);
    gemm_relu<128><<<dim3(gemm_m_blocks, 2), blk, 0, stream>>>(z, W0, b0, h1, n);

    // ---------------- Layer 1 ----------------
    hipMemsetAsync(cntH, 0, (size_t)2 * n * sizeof(int), stream);
    hist_both<<<histb, blk, 0, stream>>>(hd1, EH, cntH, sd1, ES, cntS);
    scan_phase1<<<dim3(nb, 2), blk, 0, stream>>>(cntH, cntS, bsum, n, nb);
    scan_phase2<<<1, 128, 0, stream>>>(bsum, nb);
    scan_phase3<<<dim3(nb, 2), blk, 0, stream>>>(cntH, cntS, bsum, rpH, curH, rpS, curS, n, nb);
    order_both<<<histb, blk, 0, stream>>>(hs1, hd1, EH, curH, srcH, ss1, sd1, ES, curS, srcS);
    aggregate_z<<<agg_blocks, blk, 0, stream>>>(
        (const float4*)h1, (const float4*)hbar1, rpH, srcH, rpS, srcS, (float4*)z, n);
    gemm_relu<47><<<dim3(gemm_m_blocks, 1), blk, 0, stream>>>(z, W1, b1, (float*)d_out, n);
}

// Round 4
// 458.827 us; speedup vs baseline: 6.3039x; 1.2142x over previous
//
#include <hip/hip_runtime.h>

// N=50000, D=128 (both layers), K=256, EH=500000, ES=250000.
#define D_FEAT 128
#define K_DIM  256

typedef __attribute__((ext_vector_type(8))) short bf16x8;
typedef __attribute__((ext_vector_type(4))) float f32x4;

__device__ __forceinline__ unsigned short f2b(float f) {
    union { float f; unsigned u; } cv; cv.f = f;
    return (unsigned short)((cv.u + 0x7fffu + ((cv.u >> 16) & 1u)) >> 16);
}

// unpack uint4 = 8 bf16 (memory order: low half of word = even element) and accumulate
__device__ __forceinline__ void addu4(float* a, uint4 v) {
    union { unsigned u; float f; } c;
    c.u = v.x << 16;         a[0] += c.f;
    c.u = v.x & 0xffff0000u; a[1] += c.f;
    c.u = v.y << 16;         a[2] += c.f;
    c.u = v.y & 0xffff0000u; a[3] += c.f;
    c.u = v.z << 16;         a[4] += c.f;
    c.u = v.z & 0xffff0000u; a[5] += c.f;
    c.u = v.w << 16;         a[6] += c.f;
    c.u = v.w & 0xffff0000u; a[7] += c.f;
}

// ---------------- CSR build ----------------

__global__ __launch_bounds__(256)
void hist_both(const int* __restrict__ hd, int EH, int* __restrict__ cntH,
               const int* __restrict__ sd, int ES, int* __restrict__ cntS) {
    int i = blockIdx.x * blockDim.x + threadIdx.x;
    if (i < EH) {
        atomicAdd(&cntH[hd[i]], 1);
    } else {
        int j = i - EH;
        if (j < ES) atomicAdd(&cntS[sd[j]], 1);
    }
}

__global__ __launch_bounds__(256)
void scan_phase1(const int* __restrict__ cntH, const int* __restrict__ cntS,
                 int* __restrict__ blockSums, int n, int nb) {
    const int* cnt = blockIdx.y ? cntS : cntH;
    int t = threadIdx.x;
    int base = blockIdx.x * 1024 + t * 4;
    int s = 0;
    #pragma unroll
    for (int i = 0; i < 4; ++i) { int g = base + i; if (g < n) s += cnt[g]; }
    __shared__ int sh[256];
    sh[t] = s;
    __syncthreads();
    for (int off = 128; off > 0; off >>= 1) {
        if (t < off) sh[t] += sh[t + off];
        __syncthreads();
    }
    if (t == 0) blockSums[blockIdx.y * nb + blockIdx.x] = sh[0];
}

__global__ __launch_bounds__(128)
void scan_phase2(int* __restrict__ blockSums, int nb) {
    __shared__ int sh[128];
    int t = threadIdx.x;
    if (t < 2 * nb) sh[t] = blockSums[t];
    __syncthreads();
    if (t < 2) {
        int run = 0;
        for (int i = 0; i < nb; ++i) { int v = sh[t * nb + i]; sh[t * nb + i] = run; run += v; }
    }
    __syncthreads();
    if (t < 2 * nb) blockSums[t] = sh[t];
}

__global__ __launch_bounds__(256)
void scan_phase3(const int* __restrict__ cntH, const int* __restrict__ cntS,
                 const int* __restrict__ blockSums,
                 int* __restrict__ rpH, int* __restrict__ curH,
                 int* __restrict__ rpS, int* __restrict__ curS, int n, int nb) {
    const int* cnt = blockIdx.y ? cntS : cntH;
    int* rp  = blockIdx.y ? rpS : rpH;
    int* cur = blockIdx.y ? curS : curH;
    int t = threadIdx.x;
    int base = blockIdx.x * 1024 + t * 4;
    int v[4];
    int s = 0;
    #pragma unroll
    for (int i = 0; i < 4; ++i) { int g = base + i; v[i] = (g < n) ? cnt[g] : 0; s += v[i]; }
    __shared__ int sh[256];
    sh[t] = s;
    __syncthreads();
    for (int off = 1; off < 256; off <<= 1) {
        int x = (t >= off) ? sh[t - off] : 0;
        __syncthreads();
        sh[t] += x;
        __syncthreads();
    }
    int excl = blockSums[blockIdx.y * nb + blockIdx.x] + (t ? sh[t - 1] : 0);
    #pragma unroll
    for (int i = 0; i < 4; ++i) {
        int g = base + i;
        if (g < n) {
            rp[g] = excl; cur[g] = excl;
            excl += v[i];
            if (g == n - 1) rp[n] = excl;
        }
    }
}

__global__ __launch_bounds__(256)
void order_both(const int* __restrict__ hs, const int* __restrict__ hd, int EH,
                int* __restrict__ curH, int* __restrict__ srcH,
                const int* __restrict__ ss, const int* __restrict__ sd, int ES,
                int* __restrict__ curS, int* __restrict__ srcS) {
    int i = blockIdx.x * blockDim.x + threadIdx.x;
    if (i < EH) {
        int p = atomicAdd(&curH[hd[i]], 1);
        srcH[p] = hs[i];
    } else {
        int j = i - EH;
        if (j < ES) {
            int p = atomicAdd(&curS[sd[j]], 1);
            srcS[p] = ss[j];
        }
    }
}

// ---------------- bf16 table prep ----------------
// hb = bf16(HBar), db = bf16(H - HBar); nvec = n*128/4 float4 chunks.
__global__ __launch_bounds__(256)
void prep_tables(const float4* __restrict__ H, const float4* __restrict__ HBar,
                 ushort4* __restrict__ hb, ushort4* __restrict__ db, int nvec) {
    int i = blockIdx.x * 256 + threadIdx.x;
    if (i >= nvec) return;
    float4 h = H[i], b = HBar[i];
    hb[i] = make_ushort4(f2b(b.x), f2b(b.y), f2b(b.z), f2b(b.w));
    db[i] = make_ushort4(f2b(h.x - b.x), f2b(h.y - b.y), f2b(h.z - b.z), f2b(h.w - b.w));
}

// W0 [128][256] -> bf16; W1 [47][256] -> bf16 zero-padded to [64][256].
__global__ __launch_bounds__(256)
void conv_weights(const float* __restrict__ W0, unsigned short* __restrict__ Wb0,
                  const float* __restrict__ W1, unsigned short* __restrict__ Wb1) {
    int i = blockIdx.x * 256 + threadIdx.x;
    if (i < 128 * 256) Wb0[i] = f2b(W0[i]);
    if (i < 64 * 256) {
        int r = i >> 8;
        Wb1[i] = (r < 47) ? f2b(W1[i]) : (unsigned short)0;
    }
}

// ---------------- fused aggregation + z assembly (bf16) ----------------
// 16 lanes per node, each lane owns one uint4 (8 bf16 = 16B) of the 256B row.
__global__ __launch_bounds__(256)
void aggregate_z(const float* __restrict__ H, const uint4* __restrict__ HB,
                 const uint4* __restrict__ DB,
                 const int* __restrict__ rpH, const int* __restrict__ srcH,
                 const int* __restrict__ rpS, const int* __restrict__ srcS,
                 uint4* __restrict__ z, int n) {
    int g    = blockIdx.x * 16 + (threadIdx.x >> 4);
    int lane = threadIdx.x & 15;
    if (g >= n) return;

    int hb_ = rpH[g], he = rpH[g + 1];
    int sb  = rpS[g], se = rpS[g + 1];

    float a[8] = {0, 0, 0, 0, 0, 0, 0, 0};
    int e = hb_;
    for (; e + 4 <= he; e += 4) {
        int s0 = srcH[e], s1 = srcH[e + 1], s2 = srcH[e + 2], s3 = srcH[e + 3];
        uint4 v0 = HB[(size_t)s0 * 16 + lane];
        uint4 v1 = HB[(size_t)s1 * 16 + lane];
        uint4 v2 = HB[(size_t)s2 * 16 + lane];
        uint4 v3 = HB[(size_t)s3 * 16 + lane];
        addu4(a, v0); addu4(a, v1); addu4(a, v2); addu4(a, v3);
    }
    for (; e < he; ++e) addu4(a, HB[(size_t)srcH[e] * 16 + lane]);

    float d[8] = {0, 0, 0, 0, 0, 0, 0, 0};
    e = sb;
    for (; e + 4 <= se; e += 4) {
        int s0 = srcS[e], s1 = srcS[e + 1], s2 = srcS[e + 2], s3 = srcS[e + 3];
        uint4 v0 = DB[(size_t)s0 * 16 + lane];
        uint4 v1 = DB[(size_t)s1 * 16 + lane];
        uint4 v2 = DB[(size_t)s2 * 16 + lane];
        uint4 v3 = DB[(size_t)s3 * 16 + lane];
        addu4(d, v0); addu4(d, v1); addu4(d, v2); addu4(d, v3);
    }
    for (; e < se; ++e) addu4(d, DB[(size_t)srcS[e] * 16 + lane]);

    float rH = 1.0f / fmaxf((float)(he - hb_), 1.0f);
    float rS = 1.0f / fmaxf((float)(se - sb), 1.0f);

    float nb0 = a[0] * rH + d[0] * rS, nb1 = a[1] * rH + d[1] * rS;
    float nb2 = a[2] * rH + d[2] * rS, nb3 = a[3] * rH + d[3] * rS;
    float nb4 = a[4] * rH + d[4] * rS, nb5 = a[5] * rH + d[5] * rS;
    float nb6 = a[6] * rH + d[6] * rS, nb7 = a[7] * rH + d[7] * rS;
    uint4 rv;
    rv.x = (unsigned)f2b(nb0) | ((unsigned)f2b(nb1) << 16);
    rv.y = (unsigned)f2b(nb2) | ((unsigned)f2b(nb3) << 16);
    rv.z = (unsigned)f2b(nb4) | ((unsigned)f2b(nb5) << 16);
    rv.w = (unsigned)f2b(nb6) | ((unsigned)f2b(nb7) << 16);
    z[(size_t)g * 32 + 16 + lane] = rv;     // right half: h_neigh

    const float4* H4 = (const float4*)H;    // left half: bf16(H row g)
    float4 l0 = H4[(size_t)g * 32 + lane * 2];
    float4 l1 = H4[(size_t)g * 32 + lane * 2 + 1];
    uint4 lv;
    lv.x = (unsigned)f2b(l0.x) | ((unsigned)f2b(l0.y) << 16);
    lv.y = (unsigned)f2b(l0.z) | ((unsigned)f2b(l0.w) << 16);
    lv.z = (unsigned)f2b(l1.x) | ((unsigned)f2b(l1.y) << 16);
    lv.w = (unsigned)f2b(l1.z) | ((unsigned)f2b(l1.w) << 16);
    z[(size_t)g * 32 + lane] = lv;
}

// ---------------- MFMA GEMM + bias + relu ----------------
// out[m,c] = relu(sum_k z[m,k]*W[c,k] + bias[c]); K=256, bf16 inputs, f32 out.
// Block = 4 waves; wave w computes rows [blk*64 + w*16, +16) x NT*16 cols.
template<int NT>
__global__ __launch_bounds__(256)
void gemm_mfma(const unsigned short* __restrict__ Z, const unsigned short* __restrict__ Wb,
               const float* __restrict__ bias, float* __restrict__ out, int n, int COLS) {
    int wave = threadIdx.x >> 6;
    int lane = threadIdx.x & 63;
    int m0 = blockIdx.x * 64 + wave * 16;
    int mr = m0 + (lane & 15);
    int mc = (mr < n) ? mr : (n - 1);   // clamp; stores are guarded
    int kq = lane >> 4;                 // k-quad: 0..3

    f32x4 acc[NT] = {};
    const short* Zs = (const short*)Z;
    const short* Ws = (const short*)Wb;

    #pragma unroll
    for (int k0 = 0; k0 < 8; ++k0) {
        int ko = k0 * 32 + kq * 8;
        bf16x8 aF = *(const bf16x8*)(Zs + (size_t)mc * 256 + ko);
        #pragma unroll
        for (int t = 0; t < NT; ++t) {
            bf16x8 bF = *(const bf16x8*)(Ws + (size_t)(t * 16 + (lane & 15)) * 256 + ko);
            acc[t] = __builtin_amdgcn_mfma_f32_16x16x32_bf16(aF, bF, acc[t], 0, 0, 0);
        }
    }

    int cl = lane & 15;
    int rg = (lane >> 4) * 4;
    #pragma unroll
    for (int t = 0; t < NT; ++t) {
        int c = t * 16 + cl;
        if (c >= COLS) continue;
        float bv = bias[c];
        #pragma unroll
        for (int r = 0; r < 4; ++r) {
            int m = m0 + rg + r;
            if (m < n) out[(size_t)m * COLS + c] = fmaxf(acc[t][r] + bv, 0.f);
        }
    }
}

extern "C" void kernel_launch(void* const* d_in, const int* in_sizes, int n_in,
                              void* d_out, int out_size, void* d_ws, size_t ws_size,
                              hipStream_t stream) {
    const float* x     = (const float*)d_in[0];
    const float* hbar0 = (const float*)d_in[1];
    const float* hbar1 = (const float*)d_in[2];
    const float* W0    = (const float*)d_in[3];
    const float* b0    = (const float*)d_in[4];
    const float* W1    = (const float*)d_in[5];
    const float* b1    = (const float*)d_in[6];
    const int* hs0 = (const int*)d_in[7];
    const int* hd0 = (const int*)d_in[8];
    const int* ss0 = (const int*)d_in[9];
    const int* sd0 = (const int*)d_in[10];
    const int* hs1 = (const int*)d_in[11];
    const int* hd1 = (const int*)d_in[12];
    const int* ss1 = (const int*)d_in[13];
    const int* sd1 = (const int*)d_in[14];

    const int n  = in_sizes[0] / D_FEAT;   // 50000
    const int EH = in_sizes[7];            // 500000
    const int ES = in_sizes[9];            // 250000
    const int nb = (n + 1023) / 1024;      // 49

    // ---- workspace layout ----
    int* cntH = (int*)d_ws;                 // n
    int* cntS = cntH + n;                   // n
    int* rpH  = cntS + n;                   // n+1
    int* rpS  = rpH + (n + 1);              // n+1
    int* curH = rpS + (n + 1);              // n
    int* curS = curH + n;                   // n
    int* bsum = curS + n;                   // 2*nb
    int* srcH = bsum + 2 * nb;              // EH
    int* srcS = srcH + EH;                  // ES
    size_t int_words = (size_t)(6 * n + 2) + 2 * nb + EH + ES;
    int_words = (int_words + 3) & ~(size_t)3;              // 16 B align
    float* h1 = (float*)d_ws + int_words;                  // n*128 f32
    unsigned short* hb  = (unsigned short*)(h1 + (size_t)n * D_FEAT);  // n*128 bf16
    unsigned short* db  = hb + (size_t)n * D_FEAT;                     // n*128 bf16
    unsigned short* z   = db + (size_t)n * D_FEAT;                     // n*256 bf16
    unsigned short* Wb0 = z + (size_t)n * K_DIM;                       // 128*256
    unsigned short* Wb1 = Wb0 + 128 * 256;                             // 64*256

    dim3 blk(256);
    int histb = (EH + ES + 255) / 256;
    int prepb = ((n * 32) + 255) / 256;     // n*128/4 float4 chunks
    int aggb  = (n + 15) / 16;
    int gemmb = (n + 63) / 64;

    conv_weights<<<128, blk, 0, stream>>>(W0, Wb0, W1, Wb1);

    // ---------------- Layer 0 ----------------
    hipMemsetAsync(cntH, 0, (size_t)2 * n * sizeof(int), stream);
    hist_both<<<histb, blk, 0, stream>>>(hd0, EH, cntH, sd0, ES, cntS);
    scan_phase1<<<dim3(nb, 2), blk, 0, stream>>>(cntH, cntS, bsum, n, nb);
    scan_phase2<<<1, 128, 0, stream>>>(bsum, nb);
    scan_phase3<<<dim3(nb, 2), blk, 0, stream>>>(cntH, cntS, bsum, rpH, curH, rpS, curS, n, nb);
    order_both<<<histb, blk, 0, stream>>>(hs0, hd0, EH, curH, srcH, ss0, sd0, ES, curS, srcS);
    prep_tables<<<prepb, blk, 0, stream>>>((const float4*)x, (const float4*)hbar0,
                                           (ushort4*)hb, (ushort4*)db, n * 32);
    aggregate_z<<<aggb, blk, 0, stream>>>(x, (const uint4*)hb, (const uint4*)db,
                                          rpH, srcH, rpS, srcS, (uint4*)z, n);
    gemm_mfma<8><<<gemmb, blk, 0, stream>>>(z, Wb0, b0, h1, n, 128);

    // ---------------- Layer 1 ----------------
    hipMemsetAsync(cntH, 0, (size_t)2 * n * sizeof(int), stream);
    hist_both<<<histb, blk, 0, stream>>>(hd1, EH, cntH, sd1, ES, cntS);
    scan_phase1<<<dim3(nb, 2), blk, 0, stream>>>(cntH, cntS, bsum, n, nb);
    scan_phase2<<<1, 128, 0, stream>>>(bsum, nb);
    scan_phase3<<<dim3(nb, 2), blk, 0, stream>>>(cntH, cntS, bsum, rpH, curH, rpS, curS, n, nb);
    order_both<<<histb, blk, 0, stream>>>(hs1, hd1, EH, curH, srcH, ss1, sd1, ES, curS, srcS);
    prep_tables<<<prepb, blk, 0, stream>>>((const float4*)h1, (const float4*)hbar1,
                                           (ushort4*)hb, (ushort4*)db, n * 32);
    aggregate_z<<<aggb, blk, 0, stream>>>(h1, (const uint4*)hb, (const uint4*)db,
                                          rpH, srcH, rpS, srcS, (uint4*)z, n);
    gemm_mfma<3><<<gemmb, blk, 0, stream>>>(z, Wb1, b1, (float*)d_out, n, 47);
}

// Round 5
// 398.837 us; speedup vs baseline: 7.2520x; 1.1504x over previous
//
#include <hip/hip_runtime.h>

// N=50000, D=128 (both layers), K=256, EH=500000, ES=250000.
#define D_FEAT 128
#define K_DIM  256

typedef __attribute__((ext_vector_type(8))) short bf16x8;
typedef __attribute__((ext_vector_type(4))) float f32x4;

__device__ __forceinline__ unsigned short f2b(float f) {
    union { float f; unsigned u; } cv; cv.f = f;
    return (unsigned short)((cv.u + 0x7fffu + ((cv.u >> 16) & 1u)) >> 16);
}

__device__ __forceinline__ void addu4(float* a, uint4 v) {
    union { unsigned u; float f; } c;
    c.u = v.x << 16;         a[0] += c.f;
    c.u = v.x & 0xffff0000u; a[1] += c.f;
    c.u = v.y << 16;         a[2] += c.f;
    c.u = v.y & 0xffff0000u; a[3] += c.f;
    c.u = v.z << 16;         a[4] += c.f;
    c.u = v.z & 0xffff0000u; a[5] += c.f;
    c.u = v.w << 16;         a[6] += c.f;
    c.u = v.w & 0xffff0000u; a[7] += c.f;
}

// edge-array offset within the concatenated [H0|S0|H1|S1] space
__device__ __forceinline__ long yoff(int y, int EH, int ES) {
    return (long)((y + 1) >> 1) * EH + (long)(y >> 1) * ES;
}

// ---------------- CSR build (both layers fused; y in 0..3) ----------------

__global__ __launch_bounds__(256)
void hist4(const int* __restrict__ hd0, const int* __restrict__ sd0,
           const int* __restrict__ hd1, const int* __restrict__ sd1,
           int EH, int ES, int* __restrict__ cntAll, int n) {
    int y = blockIdx.y;
    const int* d = (y == 0) ? hd0 : (y == 1) ? sd0 : (y == 2) ? hd1 : sd1;
    int E = (y & 1) ? ES : EH;
    int i = blockIdx.x * 256 + threadIdx.x;
    if (i < E) atomicAdd(&cntAll[y * n + d[i]], 1);
}

__global__ __launch_bounds__(256)
void scan_phase1(const int* __restrict__ cntAll, int* __restrict__ blockSums,
                 int n, int nb) {
    const int* cnt = cntAll + blockIdx.y * n;
    int t = threadIdx.x;
    int base = blockIdx.x * 1024 + t * 4;
    int s = 0;
    #pragma unroll
    for (int i = 0; i < 4; ++i) { int g = base + i; if (g < n) s += cnt[g]; }
    __shared__ int sh[256];
    sh[t] = s;
    __syncthreads();
    for (int off = 128; off > 0; off >>= 1) {
        if (t < off) sh[t] += sh[t + off];
        __syncthreads();
    }
    if (t == 0) blockSums[blockIdx.y * nb + blockIdx.x] = sh[0];
}

// 4*nb <= 256 partial sums; 4 sequential scans.
__global__ __launch_bounds__(256)
void scan_phase2(int* __restrict__ blockSums, int nb) {
    __shared__ int sh[256];
    int t = threadIdx.x;
    if (t < 4 * nb) sh[t] = blockSums[t];
    __syncthreads();
    if (t < 4) {
        int run = 0;
        for (int i = 0; i < nb; ++i) { int v = sh[t * nb + i]; sh[t * nb + i] = run; run += v; }
    }
    __syncthreads();
    if (t < 4 * nb) blockSums[t] = sh[t];
}

// Writes rp (exclusive scan) and initializes per-bucket cursors at 256-node
// boundaries (bcur[y][g>>8] = rp[g]).
__global__ __launch_bounds__(256)
void scan_phase3(const int* __restrict__ cntAll, const int* __restrict__ blockSums,
                 int* __restrict__ rpAll, int* __restrict__ bcur,
                 int n, int nb, int nb2) {
    int y = blockIdx.y;
    const int* cnt = cntAll + y * n;
    int* rp = rpAll + (size_t)y * (n + 1);
    int t = threadIdx.x;
    int base = blockIdx.x * 1024 + t * 4;
    int v[4];
    int s = 0;
    #pragma unroll
    for (int i = 0; i < 4; ++i) { int g = base + i; v[i] = (g < n) ? cnt[g] : 0; s += v[i]; }
    __shared__ int sh[256];
    sh[t] = s;
    __syncthreads();
    for (int off = 1; off < 256; off <<= 1) {
        int x = (t >= off) ? sh[t - off] : 0;
        __syncthreads();
        sh[t] += x;
        __syncthreads();
    }
    int excl = blockSums[y * nb + blockIdx.x] + (t ? sh[t - 1] : 0);
    #pragma unroll
    for (int i = 0; i < 4; ++i) {
        int g = base + i;
        if (g < n) {
            rp[g] = excl;
            if (!(g & 255)) bcur[y * nb2 + (g >> 8)] = excl;
            excl += v[i];
            if (g == n - 1) rp[n] = excl;
        }
    }
}

// Phase A: bin edges into 256-node dst buckets. Block-aggregated reservation
// -> records written bucket-contiguously (dense lines).
#define EPB 4096
__global__ __launch_bounds__(256)
void binA(const int* __restrict__ hs0, const int* __restrict__ hd0,
          const int* __restrict__ ss0, const int* __restrict__ sd0,
          const int* __restrict__ hs1, const int* __restrict__ hd1,
          const int* __restrict__ ss1, const int* __restrict__ sd1,
          int EH, int ES, int* __restrict__ bcur, uint2* __restrict__ recs,
          int nb2) {
    int y = blockIdx.y;
    const int* src = (y == 0) ? hs0 : (y == 1) ? ss0 : (y == 2) ? hs1 : ss1;
    const int* dst = (y == 0) ? hd0 : (y == 1) ? sd0 : (y == 2) ? hd1 : sd1;
    int E = (y & 1) ? ES : EH;
    uint2* rb = recs + yoff(y, EH, ES);

    __shared__ int cnt[256];
    int t = threadIdx.x;
    cnt[t] = 0;
    __syncthreads();
    int i0 = blockIdx.x * EPB;
    #pragma unroll
    for (int j = 0; j < 16; ++j) {
        int i = i0 + j * 256 + t;
        if (i < E) atomicAdd(&cnt[dst[i] >> 8], 1);
    }
    __syncthreads();
    int c = cnt[t];
    __syncthreads();
    if (t < nb2 && c > 0) cnt[t] = atomicAdd(&bcur[y * nb2 + t], c);
    __syncthreads();
    #pragma unroll
    for (int j = 0; j < 16; ++j) {
        int i = i0 + j * 256 + t;
        if (i < E) {
            int dd = dst[i];
            int slot = atomicAdd(&cnt[dd >> 8], 1);
            rb[slot] = make_uint2((unsigned)src[i], (unsigned)dd);
        }
    }
}

// Phase B: one block per bucket; exact CSR placement with LDS node cursors.
// Writes confined to the bucket's contiguous srcSorted slice.
__global__ __launch_bounds__(256)
void placeB(const uint2* __restrict__ recs, const int* __restrict__ rpAll,
            int* __restrict__ srcAll, int EH, int ES, int n, int nb2) {
    int y = blockIdx.y;
    int b = blockIdx.x;
    const int* rp = rpAll + (size_t)y * (n + 1);
    int nodeBase = b << 8;
    int nodeEnd = min(n, nodeBase + 256);
    __shared__ int cur[256];
    int t = threadIdx.x;
    if (nodeBase + t < nodeEnd) cur[t] = rp[nodeBase + t];
    __syncthreads();
    long off = yoff(y, EH, ES);
    const uint2* rb = recs + off;
    int* sb = srcAll + off;
    int e0 = rp[nodeBase], e1 = rp[nodeEnd];
    for (int e = e0 + t; e < e1; e += 256) {
        uint2 r = rb[e];
        int p = atomicAdd(&cur[(int)r.y - nodeBase], 1);
        sb[p] = (int)r.x;
    }
}

// ---------------- bf16 table prep ----------------
__global__ __launch_bounds__(256)
void prep_tables(const float4* __restrict__ H, const float4* __restrict__ HBar,
                 ushort4* __restrict__ hb, ushort4* __restrict__ db, int nvec) {
    int i = blockIdx.x * 256 + threadIdx.x;
    if (i >= nvec) return;
    float4 h = H[i], b = HBar[i];
    hb[i] = make_ushort4(f2b(b.x), f2b(b.y), f2b(b.z), f2b(b.w));
    db[i] = make_ushort4(f2b(h.x - b.x), f2b(h.y - b.y), f2b(h.z - b.z), f2b(h.w - b.w));
}

__global__ __launch_bounds__(256)
void conv_weights(const float* __restrict__ W0, unsigned short* __restrict__ Wb0,
                  const float* __restrict__ W1, unsigned short* __restrict__ Wb1) {
    int i = blockIdx.x * 256 + threadIdx.x;
    if (i < 128 * 256) Wb0[i] = f2b(W0[i]);
    if (i < 64 * 256) {
        int r = i >> 8;
        Wb1[i] = (r < 47) ? f2b(W1[i]) : (unsigned short)0;
    }
}

// ---------------- fused aggregation + z assembly (bf16) ----------------
__global__ __launch_bounds__(256)
void aggregate_z(const float* __restrict__ H, const uint4* __restrict__ HB,
                 const uint4* __restrict__ DB,
                 const int* __restrict__ rpH, const int* __restrict__ srcH,
                 const int* __restrict__ rpS, const int* __restrict__ srcS,
                 uint4* __restrict__ z, int n) {
    int g    = blockIdx.x * 16 + (threadIdx.x >> 4);
    int lane = threadIdx.x & 15;
    if (g >= n) return;

    int hb_ = rpH[g], he = rpH[g + 1];
    int sb  = rpS[g], se = rpS[g + 1];

    float a[8] = {0, 0, 0, 0, 0, 0, 0, 0};
    int e = hb_;
    for (; e + 4 <= he; e += 4) {
        int s0 = srcH[e], s1 = srcH[e + 1], s2 = srcH[e + 2], s3 = srcH[e + 3];
        uint4 v0 = HB[(size_t)s0 * 16 + lane];
        uint4 v1 = HB[(size_t)s1 * 16 + lane];
        uint4 v2 = HB[(size_t)s2 * 16 + lane];
        uint4 v3 = HB[(size_t)s3 * 16 + lane];
        addu4(a, v0); addu4(a, v1); addu4(a, v2); addu4(a, v3);
    }
    for (; e < he; ++e) addu4(a, HB[(size_t)srcH[e] * 16 + lane]);

    float d[8] = {0, 0, 0, 0, 0, 0, 0, 0};
    e = sb;
    for (; e + 4 <= se; e += 4) {
        int s0 = srcS[e], s1 = srcS[e + 1], s2 = srcS[e + 2], s3 = srcS[e + 3];
        uint4 v0 = DB[(size_t)s0 * 16 + lane];
        uint4 v1 = DB[(size_t)s1 * 16 + lane];
        uint4 v2 = DB[(size_t)s2 * 16 + lane];
        uint4 v3 = DB[(size_t)s3 * 16 + lane];
        addu4(d, v0); addu4(d, v1); addu4(d, v2); addu4(d, v3);
    }
    for (; e < se; ++e) addu4(d, DB[(size_t)srcS[e] * 16 + lane]);

    float rH = 1.0f / fmaxf((float)(he - hb_), 1.0f);
    float rS = 1.0f / fmaxf((float)(se - sb), 1.0f);

    float nb0 = a[0] * rH + d[0] * rS, nb1 = a[1] * rH + d[1] * rS;
    float nb2 = a[2] * rH + d[2] * rS, nb3 = a[3] * rH + d[3] * rS;
    float nb4 = a[4] * rH + d[4] * rS, nb5 = a[5] * rH + d[5] * rS;
    float nb6 = a[6] * rH + d[6] * rS, nb7 = a[7] * rH + d[7] * rS;
    uint4 rv;
    rv.x = (unsigned)f2b(nb0) | ((unsigned)f2b(nb1) << 16);
    rv.y = (unsigned)f2b(nb2) | ((unsigned)f2b(nb3) << 16);
    rv.z = (unsigned)f2b(nb4) | ((unsigned)f2b(nb5) << 16);
    rv.w = (unsigned)f2b(nb6) | ((unsigned)f2b(nb7) << 16);
    z[(size_t)g * 32 + 16 + lane] = rv;

    const float4* H4 = (const float4*)H;
    float4 l0 = H4[(size_t)g * 32 + lane * 2];
    float4 l1 = H4[(size_t)g * 32 + lane * 2 + 1];
    uint4 lv;
    lv.x = (unsigned)f2b(l0.x) | ((unsigned)f2b(l0.y) << 16);
    lv.y = (unsigned)f2b(l0.z) | ((unsigned)f2b(l0.w) << 16);
    lv.z = (unsigned)f2b(l1.x) | ((unsigned)f2b(l1.y) << 16);
    lv.w = (unsigned)f2b(l1.z) | ((unsigned)f2b(l1.w) << 16);
    z[(size_t)g * 32 + lane] = lv;
}

// ---------------- MFMA GEMM + bias + relu ----------------
template<int NT>
__global__ __launch_bounds__(256)
void gemm_mfma(const unsigned short* __restrict__ Z, const unsigned short* __restrict__ Wb,
               const float* __restrict__ bias, float* __restrict__ out, int n, int COLS) {
    int wave = threadIdx.x >> 6;
    int lane = threadIdx.x & 63;
    int m0 = blockIdx.x * 64 + wave * 16;
    int mr = m0 + (lane & 15);
    int mc = (mr < n) ? mr : (n - 1);
    int kq = lane >> 4;

    f32x4 acc[NT] = {};
    const short* Zs = (const short*)Z;
    const short* Ws = (const short*)Wb;

    #pragma unroll
    for (int k0 = 0; k0 < 8; ++k0) {
        int ko = k0 * 32 + kq * 8;
        bf16x8 aF = *(const bf16x8*)(Zs + (size_t)mc * 256 + ko);
        #pragma unroll
        for (int t = 0; t < NT; ++t) {
            bf16x8 bF = *(const bf16x8*)(Ws + (size_t)(t * 16 + (lane & 15)) * 256 + ko);
            acc[t] = __builtin_amdgcn_mfma_f32_16x16x32_bf16(aF, bF, acc[t], 0, 0, 0);
        }
    }

    int cl = lane & 15;
    int rg = (lane >> 4) * 4;
    #pragma unroll
    for (int t = 0; t < NT; ++t) {
        int c = t * 16 + cl;
        if (c >= COLS) continue;
        float bv = bias[c];
        #pragma unroll
        for (int r = 0; r < 4; ++r) {
            int m = m0 + rg + r;
            if (m < n) out[(size_t)m * COLS + c] = fmaxf(acc[t][r] + bv, 0.f);
        }
    }
}

extern "C" void kernel_launch(void* const* d_in, const int* in_sizes, int n_in,
                              void* d_out, int out_size, void* d_ws, size_t ws_size,
                              hipStream_t stream) {
    const float* x     = (const float*)d_in[0];
    const float* hbar0 = (const float*)d_in[1];
    const float* hbar1 = (const float*)d_in[2];
    const float* W0    = (const float*)d_in[3];
    const float* b0    = (const float*)d_in[4];
    const float* W1    = (const float*)d_in[5];
    const float* b1    = (const float*)d_in[6];
    const int* hs0 = (const int*)d_in[7];
    const int* hd0 = (const int*)d_in[8];
    const int* ss0 = (const int*)d_in[9];
    const int* sd0 = (const int*)d_in[10];
    const int* hs1 = (const int*)d_in[11];
    const int* hd1 = (const int*)d_in[12];
    const int* ss1 = (const int*)d_in[13];
    const int* sd1 = (const int*)d_in[14];

    const int n   = in_sizes[0] / D_FEAT;   // 50000
    const int EH  = in_sizes[7];            // 500000
    const int ES  = in_sizes[9];            // 250000
    const int nb  = (n + 1023) / 1024;      // 49  (scan blocks per etype)
    const int nb2 = (n + 255) / 256;        // 196 (dst buckets per etype)

    // ---- workspace layout ----
    int* cntAll = (int*)d_ws;                        // 4n
    int* rpAll  = cntAll + 4 * (size_t)n;            // 4(n+1)
    int* bcur   = rpAll + 4 * (size_t)(n + 1);       // 4*nb2
    int* bsum   = bcur + 4 * nb2;                    // 4*nb
    int* srcAll = bsum + 4 * nb;                     // 2EH+2ES
    size_t int_words = 4 * (size_t)n + 4 * (size_t)(n + 1) + 4 * nb2 + 4 * nb
                     + 2 * (size_t)EH + 2 * (size_t)ES;
    int_words = (int_words + 3) & ~(size_t)3;                          // 16 B align
    float* h1 = (float*)d_ws + int_words;                              // n*128 f32
    unsigned short* hb  = (unsigned short*)(h1 + (size_t)n * D_FEAT);  // n*128 bf16
    unsigned short* db  = hb + (size_t)n * D_FEAT;                     // n*128 bf16
    unsigned short* z   = db + (size_t)n * D_FEAT;                     // n*256 bf16
    unsigned short* Wb0 = z + (size_t)n * K_DIM;                       // 128*256
    unsigned short* Wb1 = Wb0 + 128 * 256;                             // 64*256
    uint2* recs = (uint2*)z;   // overlay: records dead before z is written

    const int* rpH0 = rpAll;
    const int* rpS0 = rpAll + (size_t)(n + 1);
    const int* rpH1 = rpAll + 2 * (size_t)(n + 1);
    const int* rpS1 = rpAll + 3 * (size_t)(n + 1);
    int* srcH0 = srcAll;
    int* srcS0 = srcAll + (size_t)EH;
    int* srcH1 = srcAll + (size_t)EH + ES;
    int* srcS1 = srcAll + 2 * (size_t)EH + ES;

    dim3 blk(256);
    int histb = (EH + 255) / 256;
    int binb  = (EH + EPB - 1) / EPB;
    int prepb = ((n * 32) + 255) / 256;
    int aggb  = (n + 15) / 16;
    int gemmb = (n + 63) / 64;

    // ---- CSR build for BOTH layers (feature-independent) ----
    hipMemsetAsync(cntAll, 0, 4 * (size_t)n * sizeof(int), stream);
    conv_weights<<<128, blk, 0, stream>>>(W0, Wb0, W1, Wb1);
    hist4<<<dim3(histb, 4), blk, 0, stream>>>(hd0, sd0, hd1, sd1, EH, ES, cntAll, n);
    scan_phase1<<<dim3(nb, 4), blk, 0, stream>>>(cntAll, bsum, n, nb);
    scan_phase2<<<1, blk, 0, stream>>>(bsum, nb);
    scan_phase3<<<dim3(nb, 4), blk, 0, stream>>>(cntAll, bsum, rpAll, bcur, n, nb, nb2);
    binA<<<dim3(binb, 4), blk, 0, stream>>>(hs0, hd0, ss0, sd0, hs1, hd1, ss1, sd1,
                                            EH, ES, bcur, recs, nb2);
    placeB<<<dim3(nb2, 4), blk, 0, stream>>>(recs, rpAll, srcAll, EH, ES, n, nb2);

    // ---------------- Layer 0 ----------------
    prep_tables<<<prepb, blk, 0, stream>>>((const float4*)x, (const float4*)hbar0,
                                           (ushort4*)hb, (ushort4*)db, n * 32);
    aggregate_z<<<aggb, blk, 0, stream>>>(x, (const uint4*)hb, (const uint4*)db,
                                          rpH0, srcH0, rpS0, srcS0, (uint4*)z, n);
    gemm_mfma<8><<<gemmb, blk, 0, stream>>>(z, Wb0, b0, h1, n, 128);

    // ---------------- Layer 1 ----------------
    prep_tables<<<prepb, blk, 0, stream>>>((const float4*)h1, (const float4*)hbar1,
                                           (ushort4*)hb, (ushort4*)db, n * 32);
    aggregate_z<<<aggb, blk, 0, stream>>>(h1, (const uint4*)hb, (const uint4*)db,
                                          rpH1, srcH1, rpS1, srcS1, (uint4*)z, n);
    gemm_mfma<3><<<gemmb, blk, 0, stream>>>(z, Wb1, b1, (float*)d_out, n, 47);
}

// Round 7
// 353.156 us; speedup vs baseline: 8.1901x; 1.1294x over previous
//
#include <hip/hip_runtime.h>

// N=50000, D=128 (both layers), K=256, EH=500000, ES=250000.
#define D_FEAT 128
#define K_DIM  256
#define EPB 4096

typedef __attribute__((ext_vector_type(8))) short bf16x8;
typedef __attribute__((ext_vector_type(4))) float f32x4;

__device__ __forceinline__ unsigned short f2b(float f) {
    union { float f; unsigned u; } cv; cv.f = f;
    return (unsigned short)((cv.u + 0x7fffu + ((cv.u >> 16) & 1u)) >> 16);
}

__device__ __forceinline__ void addu4(float* a, uint4 v) {
    union { unsigned u; float f; } c;
    c.u = v.x << 16;         a[0] += c.f;
    c.u = v.x & 0xffff0000u; a[1] += c.f;
    c.u = v.y << 16;         a[2] += c.f;
    c.u = v.y & 0xffff0000u; a[3] += c.f;
    c.u = v.z << 16;         a[4] += c.f;
    c.u = v.z & 0xffff0000u; a[5] += c.f;
    c.u = v.w << 16;         a[6] += c.f;
    c.u = v.w & 0xffff0000u; a[7] += c.f;
}

// edge-array offset within the concatenated [H0|S0|H1|S1] space
__device__ __forceinline__ long yoff(int y, int EH, int ES) {
    return (long)((y + 1) >> 1) * EH + (long)(y >> 1) * ES;
}

// ---------------- bucket-level CSR build (both layers; y in 0..3) ----------------

// Bucket histogram: LDS-aggregated, one global atomic per (block,bucket).
__global__ __launch_bounds__(256)
void histB(const int* __restrict__ hd0, const int* __restrict__ sd0,
           const int* __restrict__ hd1, const int* __restrict__ sd1,
           int EH, int ES, int* __restrict__ bucketCnt, int nb2) {
    int y = blockIdx.y;
    const int* d = (y == 0) ? hd0 : (y == 1) ? sd0 : (y == 2) ? hd1 : sd1;
    int E = (y & 1) ? ES : EH;
    __shared__ int cnt[256];
    int t = threadIdx.x;
    cnt[t] = 0;
    __syncthreads();
    int i0 = blockIdx.x * EPB;
    #pragma unroll
    for (int j = 0; j < 16; ++j) {
        int i = i0 + j * 256 + t;
        if (i < E) atomicAdd(&cnt[d[i] >> 8], 1);
    }
    __syncthreads();
    if (t < nb2 && cnt[t] > 0) atomicAdd(&bucketCnt[y * nb2 + t], cnt[t]);
}

// Tiny: scan 4*nb2 bucket counts -> rpBucket (exclusive, +total) and binA cursors.
__global__ __launch_bounds__(64)
void scanBuckets(const int* __restrict__ bucketCnt, int* __restrict__ rpBucket,
                 int* __restrict__ bcur, int nb2) {
    int t = threadIdx.x;
    if (t < 4) {
        int run = 0;
        for (int i = 0; i < nb2; ++i) {
            rpBucket[t * (nb2 + 1) + i] = run;
            bcur[t * nb2 + i] = run;
            run += bucketCnt[t * nb2 + i];
        }
        rpBucket[t * (nb2 + 1) + nb2] = run;
    }
}

// Phase A: bin edges into 256-node dst buckets; records written bucket-contiguously.
// Record: src (24 bits) | localDst (8 bits, dst & 255) << 24.
__global__ __launch_bounds__(256)
void binA(const int* __restrict__ hs0, const int* __restrict__ hd0,
          const int* __restrict__ ss0, const int* __restrict__ sd0,
          const int* __restrict__ hs1, const int* __restrict__ hd1,
          const int* __restrict__ ss1, const int* __restrict__ sd1,
          int EH, int ES, int* __restrict__ bcur, unsigned* __restrict__ recs,
          int nb2) {
    int y = blockIdx.y;
    const int* src = (y == 0) ? hs0 : (y == 1) ? ss0 : (y == 2) ? hs1 : ss1;
    const int* dst = (y == 0) ? hd0 : (y == 1) ? sd0 : (y == 2) ? hd1 : sd1;
    int E = (y & 1) ? ES : EH;
    unsigned* rb = recs + yoff(y, EH, ES);

    __shared__ int cnt[256];
    int t = threadIdx.x;
    cnt[t] = 0;
    __syncthreads();
    int i0 = blockIdx.x * EPB;
    #pragma unroll
    for (int j = 0; j < 16; ++j) {
        int i = i0 + j * 256 + t;
        if (i < E) atomicAdd(&cnt[dst[i] >> 8], 1);
    }
    __syncthreads();
    int c = cnt[t];
    __syncthreads();
    if (t < nb2 && c > 0) cnt[t] = atomicAdd(&bcur[y * nb2 + t], c);
    __syncthreads();
    #pragma unroll
    for (int j = 0; j < 16; ++j) {
        int i = i0 + j * 256 + t;
        if (i < E) {
            int dd = dst[i];
            int slot = atomicAdd(&cnt[dd >> 8], 1);
            rb[slot] = (unsigned)src[i] | ((unsigned)(dd & 255) << 24);
        }
    }
}

// Phase B: one block per bucket. LDS per-node hist -> scan -> writes rp (node-level
// CSR offsets) and places srcs into the bucket's contiguous srcSorted slice.
__global__ __launch_bounds__(256)
void placeB(const unsigned* __restrict__ recs, const int* __restrict__ rpBucket,
            int* __restrict__ rpAll, int* __restrict__ srcAll,
            int EH, int ES, int n, int nb2) {
    int y = blockIdx.y;
    int b = blockIdx.x;
    int E = (y & 1) ? ES : EH;
    int* rp = rpAll + (size_t)y * (n + 1);
    long off = yoff(y, EH, ES);
    const unsigned* rb = recs + off;
    int* sb = srcAll + off;
    int e0 = rpBucket[y * (nb2 + 1) + b];
    int e1 = rpBucket[y * (nb2 + 1) + b + 1];
    int nodeBase = b << 8;

    __shared__ int cnt[256];
    __shared__ int sh[256];
    int t = threadIdx.x;
    cnt[t] = 0;
    __syncthreads();
    for (int e = e0 + t; e < e1; e += 256)
        atomicAdd(&cnt[rb[e] >> 24], 1);
    __syncthreads();
    sh[t] = cnt[t];
    __syncthreads();
    for (int o = 1; o < 256; o <<= 1) {
        int x = (t >= o) ? sh[t - o] : 0;
        __syncthreads();
        sh[t] += x;
        __syncthreads();
    }
    int base = e0 + (t ? sh[t - 1] : 0);   // exclusive
    if (nodeBase + t < n) rp[nodeBase + t] = base;
    if (b == 0 && t == 0) rp[n] = E;
    cnt[t] = base;                          // reuse as cursor
    __syncthreads();
    for (int e = e0 + t; e < e1; e += 256) {
        unsigned r = rb[e];
        int p = atomicAdd(&cnt[r >> 24], 1);
        sb[p] = (int)(r & 0x00FFFFFFu);
    }
}

// ---------------- bf16 table prep ----------------
__global__ __launch_bounds__(256)
void prep_tables(const float4* __restrict__ H, const float4* __restrict__ HBar,
                 ushort4* __restrict__ hb, ushort4* __restrict__ db, int nvec) {
    int i = blockIdx.x * 256 + threadIdx.x;
    if (i >= nvec) return;
    float4 h = H[i], b = HBar[i];
    hb[i] = make_ushort4(f2b(b.x), f2b(b.y), f2b(b.z), f2b(b.w));
    db[i] = make_ushort4(f2b(h.x - b.x), f2b(h.y - b.y), f2b(h.z - b.z), f2b(h.w - b.w));
}

__global__ __launch_bounds__(256)
void conv_weights(const float* __restrict__ W0, unsigned short* __restrict__ Wb0,
                  const float* __restrict__ W1, unsigned short* __restrict__ Wb1) {
    int i = blockIdx.x * 256 + threadIdx.x;
    if (i < 128 * 256) Wb0[i] = f2b(W0[i]);
    if (i < 64 * 256) {
        int r = i >> 8;
        Wb1[i] = (r < 47) ? f2b(W1[i]) : (unsigned short)0;
    }
}

// ---------------- fused aggregation + z assembly (bf16) ----------------
__global__ __launch_bounds__(256)
void aggregate_z(const float* __restrict__ H, const uint4* __restrict__ HB,
                 const uint4* __restrict__ DB,
                 const int* __restrict__ rpH, const int* __restrict__ srcH,
                 const int* __restrict__ rpS, const int* __restrict__ srcS,
                 uint4* __restrict__ z, int n) {
    int g    = blockIdx.x * 16 + (threadIdx.x >> 4);
    int lane = threadIdx.x & 15;
    if (g >= n) return;

    int hb_ = rpH[g], he = rpH[g + 1];
    int sb  = rpS[g], se = rpS[g + 1];

    float a[8] = {0, 0, 0, 0, 0, 0, 0, 0};
    int e = hb_;
    for (; e + 4 <= he; e += 4) {
        int s0 = srcH[e], s1 = srcH[e + 1], s2 = srcH[e + 2], s3 = srcH[e + 3];
        uint4 v0 = HB[(size_t)s0 * 16 + lane];
        uint4 v1 = HB[(size_t)s1 * 16 + lane];
        uint4 v2 = HB[(size_t)s2 * 16 + lane];
        uint4 v3 = HB[(size_t)s3 * 16 + lane];
        addu4(a, v0); addu4(a, v1); addu4(a, v2); addu4(a, v3);
    }
    for (; e < he; ++e) addu4(a, HB[(size_t)srcH[e] * 16 + lane]);

    float d[8] = {0, 0, 0, 0, 0, 0, 0, 0};
    e = sb;
    for (; e + 4 <= se; e += 4) {
        int s0 = srcS[e], s1 = srcS[e + 1], s2 = srcS[e + 2], s3 = srcS[e + 3];
        uint4 v0 = DB[(size_t)s0 * 16 + lane];
        uint4 v1 = DB[(size_t)s1 * 16 + lane];
        uint4 v2 = DB[(size_t)s2 * 16 + lane];
        uint4 v3 = DB[(size_t)s3 * 16 + lane];
        addu4(d, v0); addu4(d, v1); addu4(d, v2); addu4(d, v3);
    }
    for (; e < se; ++e) addu4(d, DB[(size_t)srcS[e] * 16 + lane]);

    float rH = 1.0f / fmaxf((float)(he - hb_), 1.0f);
    float rS = 1.0f / fmaxf((float)(se - sb), 1.0f);

    float nb0 = a[0] * rH + d[0] * rS, nb1 = a[1] * rH + d[1] * rS;
    float nb2 = a[2] * rH + d[2] * rS, nb3 = a[3] * rH + d[3] * rS;
    float nb4 = a[4] * rH + d[4] * rS, nb5 = a[5] * rH + d[5] * rS;
    float nb6 = a[6] * rH + d[6] * rS, nb7 = a[7] * rH + d[7] * rS;
    uint4 rv;
    rv.x = (unsigned)f2b(nb0) | ((unsigned)f2b(nb1) << 16);
    rv.y = (unsigned)f2b(nb2) | ((unsigned)f2b(nb3) << 16);
    rv.z = (unsigned)f2b(nb4) | ((unsigned)f2b(nb5) << 16);
    rv.w = (unsigned)f2b(nb6) | ((unsigned)f2b(nb7) << 16);
    z[(size_t)g * 32 + 16 + lane] = rv;

    const float4* H4 = (const float4*)H;
    float4 l0 = H4[(size_t)g * 32 + lane * 2];
    float4 l1 = H4[(size_t)g * 32 + lane * 2 + 1];
    uint4 lv;
    lv.x = (unsigned)f2b(l0.x) | ((unsigned)f2b(l0.y) << 16);
    lv.y = (unsigned)f2b(l0.z) | ((unsigned)f2b(l0.w) << 16);
    lv.z = (unsigned)f2b(l1.x) | ((unsigned)f2b(l1.y) << 16);
    lv.w = (unsigned)f2b(l1.z) | ((unsigned)f2b(l1.w) << 16);
    z[(size_t)g * 32 + lane] = lv;
}

// ---------------- MFMA GEMM + bias + relu ----------------
template<int NT>
__global__ __launch_bounds__(256)
void gemm_mfma(const unsigned short* __restrict__ Z, const unsigned short* __restrict__ Wb,
               const float* __restrict__ bias, float* __restrict__ out, int n, int COLS) {
    int wave = threadIdx.x >> 6;
    int lane = threadIdx.x & 63;
    int m0 = blockIdx.x * 64 + wave * 16;
    int mr = m0 + (lane & 15);
    int mc = (mr < n) ? mr : (n - 1);
    int kq = lane >> 4;

    f32x4 acc[NT] = {};
    const short* Zs = (const short*)Z;
    const short* Ws = (const short*)Wb;

    #pragma unroll
    for (int k0 = 0; k0 < 8; ++k0) {
        int ko = k0 * 32 + kq * 8;
        bf16x8 aF = *(const bf16x8*)(Zs + (size_t)mc * 256 + ko);
        #pragma unroll
        for (int t = 0; t < NT; ++t) {
            bf16x8 bF = *(const bf16x8*)(Ws + (size_t)(t * 16 + (lane & 15)) * 256 + ko);
            acc[t] = __builtin_amdgcn_mfma_f32_16x16x32_bf16(aF, bF, acc[t], 0, 0, 0);
        }
    }

    int cl = lane & 15;
    int rg = (lane >> 4) * 4;
    #pragma unroll
    for (int t = 0; t < NT; ++t) {
        int c = t * 16 + cl;
        if (c >= COLS) continue;
        float bv = bias[c];
        #pragma unroll
        for (int r = 0; r < 4; ++r) {
            int m = m0 + rg + r;
            if (m < n) out[(size_t)m * COLS + c] = fmaxf(acc[t][r] + bv, 0.f);
        }
    }
}

extern "C" void kernel_launch(void* const* d_in, const int* in_sizes, int n_in,
                              void* d_out, int out_size, void* d_ws, size_t ws_size,
                              hipStream_t stream) {
    const float* x     = (const float*)d_in[0];
    const float* hbar0 = (const float*)d_in[1];
    const float* hbar1 = (const float*)d_in[2];
    const float* W0    = (const float*)d_in[3];
    const float* b0    = (const float*)d_in[4];
    const float* W1    = (const float*)d_in[5];
    const float* b1    = (const float*)d_in[6];
    const int* hs0 = (const int*)d_in[7];
    const int* hd0 = (const int*)d_in[8];
    const int* ss0 = (const int*)d_in[9];
    const int* sd0 = (const int*)d_in[10];
    const int* hs1 = (const int*)d_in[11];
    const int* hd1 = (const int*)d_in[12];
    const int* ss1 = (const int*)d_in[13];
    const int* sd1 = (const int*)d_in[14];

    const int n   = in_sizes[0] / D_FEAT;   // 50000
    const int EH  = in_sizes[7];            // 500000
    const int ES  = in_sizes[9];            // 250000
    const int nb2 = (n + 255) / 256;        // 196 dst buckets per etype

    // ---- workspace layout ----
    int* bucketCnt = (int*)d_ws;                       // 4*nb2
    int* rpBucket  = bucketCnt + 4 * nb2;              // 4*(nb2+1)
    int* bcur      = rpBucket + 4 * (nb2 + 1);         // 4*nb2
    int* rpAll     = bcur + 4 * nb2;                   // 4*(n+1)
    int* srcAll    = rpAll + 4 * (size_t)(n + 1);      // 2EH+2ES
    size_t int_words = (size_t)12 * nb2 + 4 + 4 * (size_t)(n + 1)
                     + 2 * (size_t)EH + 2 * (size_t)ES;
    int_words = (int_words + 3) & ~(size_t)3;                          // 16 B align
    float* h1 = (float*)d_ws + int_words;                              // n*128 f32
    unsigned short* hb  = (unsigned short*)(h1 + (size_t)n * D_FEAT);  // n*128 bf16
    unsigned short* db  = hb + (size_t)n * D_FEAT;                     // n*128 bf16
    unsigned short* z   = db + (size_t)n * D_FEAT;                     // n*256 bf16
    unsigned short* Wb0 = z + (size_t)n * K_DIM;                       // 128*256
    unsigned short* Wb1 = Wb0 + 128 * 256;                             // 64*256
    unsigned* recs = (unsigned*)z;   // overlay: records dead before z is written

    const int* rpH0 = rpAll;
    const int* rpS0 = rpAll + (size_t)(n + 1);
    const int* rpH1 = rpAll + 2 * (size_t)(n + 1);
    const int* rpS1 = rpAll + 3 * (size_t)(n + 1);
    int* srcH0 = srcAll;
    int* srcS0 = srcAll + (size_t)EH;
    int* srcH1 = srcAll + (size_t)EH + ES;
    int* srcS1 = srcAll + 2 * (size_t)EH + ES;

    dim3 blk(256);
    int binb  = (EH + EPB - 1) / EPB;       // covers both EH and ES (guarded)
    int prepb = ((n * 32) + 255) / 256;
    int aggb  = (n + 15) / 16;
    int gemmb = (n + 63) / 64;

    // ---- CSR build for BOTH layers (feature-independent) ----
    hipMemsetAsync(bucketCnt, 0, 4 * (size_t)nb2 * sizeof(int), stream);
    conv_weights<<<128, blk, 0, stream>>>(W0, Wb0, W1, Wb1);
    histB<<<dim3(binb, 4), blk, 0, stream>>>(hd0, sd0, hd1, sd1, EH, ES, bucketCnt, nb2);
    scanBuckets<<<1, 64, 0, stream>>>(bucketCnt, rpBucket, bcur, nb2);
    binA<<<dim3(binb, 4), blk, 0, stream>>>(hs0, hd0, ss0, sd0, hs1, hd1, ss1, sd1,
                                            EH, ES, bcur, recs, nb2);
    placeB<<<dim3(nb2, 4), blk, 0, stream>>>(recs, rpBucket, rpAll, srcAll, EH, ES, n, nb2);

    // ---------------- Layer 0 ----------------
    prep_tables<<<prepb, blk, 0, stream>>>((const float4*)x, (const float4*)hbar0,
                                           (ushort4*)hb, (ushort4*)db, n * 32);
    aggregate_z<<<aggb, blk, 0, stream>>>(x, (const uint4*)hb, (const uint4*)db,
                                          rpH0, srcH0, rpS0, srcS0, (uint4*)z, n);
    gemm_mfma<8><<<gemmb, blk, 0, stream>>>(z, Wb0, b0, h1, n, 128);

    // ---------------- Layer 1 ----------------
    prep_tables<<<prepb, blk, 0, stream>>>((const float4*)h1, (const float4*)hbar1,
                                           (ushort4*)hb, (ushort4*)db, n * 32);
    aggregate_z<<<aggb, blk, 0, stream>>>(h1, (const uint4*)hb, (const uint4*)db,
                                          rpH1, srcH1, rpS1, srcS1, (uint4*)z, n);
    gemm_mfma<3><<<gemmb, blk, 0, stream>>>(z, Wb1, b1, (float*)d_out, n, 47);
}

// Round 8
// 351.245 us; speedup vs baseline: 8.2347x; 1.0054x over previous
//
#include <hip/hip_runtime.h>

// N=50000, D=128 (both layers), K=256, EH=500000, ES=250000.
#define D_FEAT 128
#define K_DIM  256
#define EPB 4096

typedef __attribute__((ext_vector_type(8))) short bf16x8;
typedef __attribute__((ext_vector_type(4))) float f32x4;

__device__ __forceinline__ unsigned short f2b(float f) {
    union { float f; unsigned u; } cv; cv.f = f;
    return (unsigned short)((cv.u + 0x7fffu + ((cv.u >> 16) & 1u)) >> 16);
}

__device__ __forceinline__ unsigned pack2(float lo, float hi) {
    return (unsigned)f2b(lo) | ((unsigned)f2b(hi) << 16);
}

__device__ __forceinline__ uint4 pack8(float4 a, float4 b) {
    return make_uint4(pack2(a.x, a.y), pack2(a.z, a.w), pack2(b.x, b.y), pack2(b.z, b.w));
}

// unpack uint4 = 8 bf16 (low half of word = even element) and accumulate
__device__ __forceinline__ void addu4(float* a, uint4 v) {
    union { unsigned u; float f; } c;
    c.u = v.x << 16;         a[0] += c.f;
    c.u = v.x & 0xffff0000u; a[1] += c.f;
    c.u = v.y << 16;         a[2] += c.f;
    c.u = v.y & 0xffff0000u; a[3] += c.f;
    c.u = v.z << 16;         a[4] += c.f;
    c.u = v.z & 0xffff0000u; a[5] += c.f;
    c.u = v.w << 16;         a[6] += c.f;
    c.u = v.w & 0xffff0000u; a[7] += c.f;
}

// edge-array offset within the concatenated [H0|S0|H1|S1] space
__device__ __forceinline__ long yoff(int y, int EH, int ES) {
    return (long)((y + 1) >> 1) * EH + (long)(y >> 1) * ES;
}

// ---------------- bucket-level CSR build (both layers; y in 0..3) ----------------

__global__ __launch_bounds__(256)
void histB(const int* __restrict__ hd0, const int* __restrict__ sd0,
           const int* __restrict__ hd1, const int* __restrict__ sd1,
           int EH, int ES, int* __restrict__ bucketCnt, int nb2) {
    int y = blockIdx.y;
    const int* d = (y == 0) ? hd0 : (y == 1) ? sd0 : (y == 2) ? hd1 : sd1;
    int E = (y & 1) ? ES : EH;
    __shared__ int cnt[256];
    int t = threadIdx.x;
    cnt[t] = 0;
    __syncthreads();
    int i0 = blockIdx.x * EPB;
    #pragma unroll
    for (int j = 0; j < 16; ++j) {
        int i = i0 + j * 256 + t;
        if (i < E) atomicAdd(&cnt[d[i] >> 8], 1);
    }
    __syncthreads();
    if (t < nb2 && cnt[t] > 0) atomicAdd(&bucketCnt[y * nb2 + t], cnt[t]);
}

__global__ __launch_bounds__(64)
void scanBuckets(const int* __restrict__ bucketCnt, int* __restrict__ rpBucket,
                 int* __restrict__ bcur, int nb2) {
    int t = threadIdx.x;
    if (t < 4) {
        int run = 0;
        for (int i = 0; i < nb2; ++i) {
            rpBucket[t * (nb2 + 1) + i] = run;
            bcur[t * nb2 + i] = run;
            run += bucketCnt[t * nb2 + i];
        }
        rpBucket[t * (nb2 + 1) + nb2] = run;
    }
}

// Record: src (24 bits) | localDst (8 bits) << 24.
__global__ __launch_bounds__(256)
void binA(const int* __restrict__ hs0, const int* __restrict__ hd0,
          const int* __restrict__ ss0, const int* __restrict__ sd0,
          const int* __restrict__ hs1, const int* __restrict__ hd1,
          const int* __restrict__ ss1, const int* __restrict__ sd1,
          int EH, int ES, int* __restrict__ bcur, unsigned* __restrict__ recs,
          int nb2) {
    int y = blockIdx.y;
    const int* src = (y == 0) ? hs0 : (y == 1) ? ss0 : (y == 2) ? hs1 : ss1;
    const int* dst = (y == 0) ? hd0 : (y == 1) ? sd0 : (y == 2) ? hd1 : sd1;
    int E = (y & 1) ? ES : EH;
    unsigned* rb = recs + yoff(y, EH, ES);

    __shared__ int cnt[256];
    int t = threadIdx.x;
    cnt[t] = 0;
    __syncthreads();
    int i0 = blockIdx.x * EPB;
    #pragma unroll
    for (int j = 0; j < 16; ++j) {
        int i = i0 + j * 256 + t;
        if (i < E) atomicAdd(&cnt[dst[i] >> 8], 1);
    }
    __syncthreads();
    int c = cnt[t];
    __syncthreads();
    if (t < nb2 && c > 0) cnt[t] = atomicAdd(&bcur[y * nb2 + t], c);
    __syncthreads();
    #pragma unroll
    for (int j = 0; j < 16; ++j) {
        int i = i0 + j * 256 + t;
        if (i < E) {
            int dd = dst[i];
            int slot = atomicAdd(&cnt[dd >> 8], 1);
            rb[slot] = (unsigned)src[i] | ((unsigned)(dd & 255) << 24);
        }
    }
}

__global__ __launch_bounds__(256)
void placeB(const unsigned* __restrict__ recs, const int* __restrict__ rpBucket,
            int* __restrict__ rpAll, int* __restrict__ srcAll,
            int EH, int ES, int n, int nb2) {
    int y = blockIdx.y;
    int b = blockIdx.x;
    int E = (y & 1) ? ES : EH;
    int* rp = rpAll + (size_t)y * (n + 1);
    long off = yoff(y, EH, ES);
    const unsigned* rb = recs + off;
    int* sb = srcAll + off;
    int e0 = rpBucket[y * (nb2 + 1) + b];
    int e1 = rpBucket[y * (nb2 + 1) + b + 1];
    int nodeBase = b << 8;

    __shared__ int cnt[256];
    __shared__ int sh[256];
    int t = threadIdx.x;
    cnt[t] = 0;
    __syncthreads();
    for (int e = e0 + t; e < e1; e += 256)
        atomicAdd(&cnt[rb[e] >> 24], 1);
    __syncthreads();
    sh[t] = cnt[t];
    __syncthreads();
    for (int o = 1; o < 256; o <<= 1) {
        int x = (t >= o) ? sh[t - o] : 0;
        __syncthreads();
        sh[t] += x;
        __syncthreads();
    }
    int base = e0 + (t ? sh[t - 1] : 0);
    if (nodeBase + t < n) rp[nodeBase + t] = base;
    if (b == 0 && t == 0) rp[n] = E;
    cnt[t] = base;
    __syncthreads();
    for (int e = e0 + t; e < e1; e += 256) {
        unsigned r = rb[e];
        int p = atomicAdd(&cnt[r >> 24], 1);
        sb[p] = (int)(r & 0x00FFFFFFu);
    }
}

// ---------------- upfront bf16 prep ----------------
// hb0=bf16(hbar0), db0=bf16(x-hbar0), hb1=bf16(hbar1), z-left=bf16(x).
// i indexes (node g = i>>4, seg = i&15); each thread handles 8 features (16B).
__global__ __launch_bounds__(256)
void prep_static(const float4* __restrict__ x, const float4* __restrict__ hbar0,
                 const float4* __restrict__ hbar1,
                 uint4* __restrict__ hb0, uint4* __restrict__ db0,
                 uint4* __restrict__ hb1, uint4* __restrict__ z, int n16) {
    int i = blockIdx.x * 256 + threadIdx.x;
    if (i >= n16) return;
    float4 xa = x[i * 2],     xb = x[i * 2 + 1];
    float4 ba = hbar0[i * 2], bb = hbar0[i * 2 + 1];
    float4 ca = hbar1[i * 2], cb = hbar1[i * 2 + 1];
    hb0[i] = pack8(ba, bb);
    db0[i] = pack8(make_float4(xa.x - ba.x, xa.y - ba.y, xa.z - ba.z, xa.w - ba.w),
                   make_float4(xb.x - bb.x, xb.y - bb.y, xb.z - bb.z, xb.w - bb.w));
    hb1[i] = pack8(ca, cb);
    int g = i >> 4, seg = i & 15;
    z[(size_t)g * 32 + seg] = pack8(xa, xb);   // z left half = bf16(x row)
}

__global__ __launch_bounds__(256)
void conv_weights(const float* __restrict__ W0, unsigned short* __restrict__ Wb0,
                  const float* __restrict__ W1, unsigned short* __restrict__ Wb1) {
    int i = blockIdx.x * 256 + threadIdx.x;
    if (i < 128 * 256) Wb0[i] = f2b(W0[i]);
    if (i < 64 * 256) {
        int r = i >> 8;
        Wb1[i] = (r < 47) ? f2b(W1[i]) : (unsigned short)0;
    }
}

// ---------------- aggregation: one full wave per node ----------------
// 64 lanes = 4 edges (j = lane>>4) x 16 feature-segments (l = lane&15, 16B each).
// Uniform trip count per wave (no divergence); shfl_xor reduction across j.
__global__ __launch_bounds__(256)
void aggregate_z(const uint4* __restrict__ HB, const uint4* __restrict__ DB,
                 const int* __restrict__ rpH, const int* __restrict__ srcH,
                 const int* __restrict__ rpS, const int* __restrict__ srcS,
                 uint4* __restrict__ z, int n) {
    int g = blockIdx.x * 4 + (threadIdx.x >> 6);
    if (g >= n) return;
    int lane = threadIdx.x & 63;
    int j = lane >> 4, l = lane & 15;

    int hb_ = rpH[g], he = rpH[g + 1];
    int sb  = rpS[g], se = rpS[g + 1];

    float a[8] = {0, 0, 0, 0, 0, 0, 0, 0};
    for (int e0 = hb_; e0 < he; e0 += 8) {
        int e1 = e0 + j, e2 = e0 + 4 + j;
        uint4 v1 = make_uint4(0, 0, 0, 0), v2 = make_uint4(0, 0, 0, 0);
        if (e1 < he) v1 = HB[(size_t)srcH[e1] * 16 + l];
        if (e2 < he) v2 = HB[(size_t)srcH[e2] * 16 + l];
        addu4(a, v1); addu4(a, v2);
    }
    float d[8] = {0, 0, 0, 0, 0, 0, 0, 0};
    for (int e0 = sb; e0 < se; e0 += 8) {
        int e1 = e0 + j, e2 = e0 + 4 + j;
        uint4 v1 = make_uint4(0, 0, 0, 0), v2 = make_uint4(0, 0, 0, 0);
        if (e1 < se) v1 = DB[(size_t)srcS[e1] * 16 + l];
        if (e2 < se) v2 = DB[(size_t)srcS[e2] * 16 + l];
        addu4(d, v1); addu4(d, v2);
    }

    float rH = 1.0f / fmaxf((float)(he - hb_), 1.0f);
    float rS = 1.0f / fmaxf((float)(se - sb), 1.0f);
    float s[8];
    #pragma unroll
    for (int i = 0; i < 8; ++i) {
        float v = a[i] * rH + d[i] * rS;
        v += __shfl_xor(v, 16);
        v += __shfl_xor(v, 32);
        s[i] = v;
    }
    if (j == 0) {
        uint4 rv = make_uint4(pack2(s[0], s[1]), pack2(s[2], s[3]),
                              pack2(s[4], s[5]), pack2(s[6], s[7]));
        z[(size_t)g * 32 + 16 + l] = rv;   // right half: h_neigh
    }
}

// ---------------- MFMA GEMM layer 0: fused epilogue ----------------
// h1 = relu(z@W0^T + b0); writes z left half = bf16(h1), db1 = bf16(h1 - hbar1).
__global__ __launch_bounds__(256)
void gemm_mfma_l0(const unsigned short* __restrict__ Z, const unsigned short* __restrict__ Wb,
                  const float* __restrict__ bias, const float* __restrict__ hbar1,
                  unsigned short* __restrict__ db1, unsigned short* __restrict__ zl, int n) {
    int wave = threadIdx.x >> 6;
    int lane = threadIdx.x & 63;
    int m0 = blockIdx.x * 64 + wave * 16;
    int mr = m0 + (lane & 15);
    int mc = (mr < n) ? mr : (n - 1);
    int kq = lane >> 4;

    f32x4 acc[8] = {};
    const short* Zs = (const short*)Z;
    const short* Ws = (const short*)Wb;

    #pragma unroll
    for (int k0 = 0; k0 < 8; ++k0) {
        int ko = k0 * 32 + kq * 8;
        bf16x8 aF = *(const bf16x8*)(Zs + (size_t)mc * 256 + ko);
        #pragma unroll
        for (int t = 0; t < 8; ++t) {
            bf16x8 bF = *(const bf16x8*)(Ws + (size_t)(t * 16 + (lane & 15)) * 256 + ko);
            acc[t] = __builtin_amdgcn_mfma_f32_16x16x32_bf16(aF, bF, acc[t], 0, 0, 0);
        }
    }

    int cl = lane & 15;
    int rg = (lane >> 4) * 4;
    #pragma unroll
    for (int r = 0; r < 4; ++r) {
        int m = m0 + rg + r;
        if (m >= n) continue;
        #pragma unroll
        for (int t = 0; t < 8; ++t) {
            int c = t * 16 + cl;
            float h = fmaxf(acc[t][r] + bias[c], 0.0f);
            float hbv = hbar1[(size_t)m * 128 + c];
            db1[(size_t)m * 128 + c] = f2b(h - hbv);
            zl[(size_t)m * 256 + c]  = f2b(h);
        }
    }
}

// ---------------- MFMA GEMM layer 1 -> f32 out ----------------
template<int NT>
__global__ __launch_bounds__(256)
void gemm_mfma(const unsigned short* __restrict__ Z, const unsigned short* __restrict__ Wb,
               const float* __restrict__ bias, float* __restrict__ out, int n, int COLS) {
    int wave = threadIdx.x >> 6;
    int lane = threadIdx.x & 63;
    int m0 = blockIdx.x * 64 + wave * 16;
    int mr = m0 + (lane & 15);
    int mc = (mr < n) ? mr : (n - 1);
    int kq = lane >> 4;

    f32x4 acc[NT] = {};
    const short* Zs = (const short*)Z;
    const short* Ws = (const short*)Wb;

    #pragma unroll
    for (int k0 = 0; k0 < 8; ++k0) {
        int ko = k0 * 32 + kq * 8;
        bf16x8 aF = *(const bf16x8*)(Zs + (size_t)mc * 256 + ko);
        #pragma unroll
        for (int t = 0; t < NT; ++t) {
            bf16x8 bF = *(const bf16x8*)(Ws + (size_t)(t * 16 + (lane & 15)) * 256 + ko);
            acc[t] = __builtin_amdgcn_mfma_f32_16x16x32_bf16(aF, bF, acc[t], 0, 0, 0);
        }
    }

    int cl = lane & 15;
    int rg = (lane >> 4) * 4;
    #pragma unroll
    for (int t = 0; t < NT; ++t) {
        int c = t * 16 + cl;
        if (c >= COLS) continue;
        float bv = bias[c];
        #pragma unroll
        for (int r = 0; r < 4; ++r) {
            int m = m0 + rg + r;
            if (m < n) out[(size_t)m * COLS + c] = fmaxf(acc[t][r] + bv, 0.f);
        }
    }
}

extern "C" void kernel_launch(void* const* d_in, const int* in_sizes, int n_in,
                              void* d_out, int out_size, void* d_ws, size_t ws_size,
                              hipStream_t stream) {
    const float* x     = (const float*)d_in[0];
    const float* hbar0 = (const float*)d_in[1];
    const float* hbar1 = (const float*)d_in[2];
    const float* W0    = (const float*)d_in[3];
    const float* b0    = (const float*)d_in[4];
    const float* W1    = (const float*)d_in[5];
    const float* b1    = (const float*)d_in[6];
    const int* hs0 = (const int*)d_in[7];
    const int* hd0 = (const int*)d_in[8];
    const int* ss0 = (const int*)d_in[9];
    const int* sd0 = (const int*)d_in[10];
    const int* hs1 = (const int*)d_in[11];
    const int* hd1 = (const int*)d_in[12];
    const int* ss1 = (const int*)d_in[13];
    const int* sd1 = (const int*)d_in[14];

    const int n   = in_sizes[0] / D_FEAT;   // 50000
    const int EH  = in_sizes[7];            // 500000
    const int ES  = in_sizes[9];            // 250000
    const int nb2 = (n + 255) / 256;        // 196 dst buckets per etype

    // ---- workspace layout ----
    int* bucketCnt = (int*)d_ws;                       // 4*nb2
    int* rpBucket  = bucketCnt + 4 * nb2;              // 4*(nb2+1)
    int* bcur      = rpBucket + 4 * (nb2 + 1);         // 4*nb2
    int* rpAll     = bcur + 4 * nb2;                   // 4*(n+1)
    int* srcAll    = rpAll + 4 * (size_t)(n + 1);      // 2EH+2ES
    unsigned* recs = (unsigned*)(srcAll + 2 * (size_t)EH + 2 * (size_t)ES); // 2EH+2ES
    size_t int_words = (size_t)12 * nb2 + 4 + 4 * (size_t)(n + 1)
                     + 4 * (size_t)EH + 4 * (size_t)ES;
    int_words = (int_words + 3) & ~(size_t)3;                          // 16 B align
    unsigned short* hb0 = (unsigned short*)((int*)d_ws + int_words);   // n*128 bf16
    unsigned short* db0 = hb0 + (size_t)n * D_FEAT;                    // n*128 bf16
    unsigned short* hb1 = db0 + (size_t)n * D_FEAT;                    // n*128 bf16
    unsigned short* db1 = hb1 + (size_t)n * D_FEAT;                    // n*128 bf16
    unsigned short* z   = db1 + (size_t)n * D_FEAT;                    // n*256 bf16
    unsigned short* Wb0 = z + (size_t)n * K_DIM;                       // 128*256
    unsigned short* Wb1 = Wb0 + 128 * 256;                             // 64*256

    const int* rpH0 = rpAll;
    const int* rpS0 = rpAll + (size_t)(n + 1);
    const int* rpH1 = rpAll + 2 * (size_t)(n + 1);
    const int* rpS1 = rpAll + 3 * (size_t)(n + 1);
    int* srcH0 = srcAll;
    int* srcS0 = srcAll + (size_t)EH;
    int* srcH1 = srcAll + (size_t)EH + ES;
    int* srcS1 = srcAll + 2 * (size_t)EH + ES;

    dim3 blk(256);
    int binb  = (EH + EPB - 1) / EPB;
    int prepb = ((n * 16) + 255) / 256;
    int aggb  = (n + 3) / 4;
    int gemmb = (n + 63) / 64;

    // ---- CSR build for BOTH layers + static prep ----
    hipMemsetAsync(bucketCnt, 0, 4 * (size_t)nb2 * sizeof(int), stream);
    conv_weights<<<128, blk, 0, stream>>>(W0, Wb0, W1, Wb1);
    histB<<<dim3(binb, 4), blk, 0, stream>>>(hd0, sd0, hd1, sd1, EH, ES, bucketCnt, nb2);
    scanBuckets<<<1, 64, 0, stream>>>(bucketCnt, rpBucket, bcur, nb2);
    binA<<<dim3(binb, 4), blk, 0, stream>>>(hs0, hd0, ss0, sd0, hs1, hd1, ss1, sd1,
                                            EH, ES, bcur, recs, nb2);
    placeB<<<dim3(nb2, 4), blk, 0, stream>>>(recs, rpBucket, rpAll, srcAll, EH, ES, n, nb2);
    prep_static<<<prepb, blk, 0, stream>>>((const float4*)x, (const float4*)hbar0,
                                           (const float4*)hbar1, (uint4*)hb0, (uint4*)db0,
                                           (uint4*)hb1, (uint4*)z, n * 16);

    // ---------------- Layer 0 ----------------
    aggregate_z<<<aggb, blk, 0, stream>>>((const uint4*)hb0, (const uint4*)db0,
                                          rpH0, srcH0, rpS0, srcS0, (uint4*)z, n);
    gemm_mfma_l0<<<gemmb, blk, 0, stream>>>(z, Wb0, b0, hbar1, db1, z, n);

    // ---------------- Layer 1 ----------------
    aggregate_z<<<aggb, blk, 0, stream>>>((const uint4*)hb1, (const uint4*)db1,
                                          rpH1, srcH1, rpS1, srcS1, (uint4*)z, n);
    gemm_mfma<3><<<gemmb, blk, 0, stream>>>(z, Wb1, b1, (float*)d_out, n, 47);
}